// Round 10
// baseline (888.462 us; speedup 1.0000x reference)
//
#include <hip/hip_runtime.h>
#include <hip/hip_cooperative_groups.h>
#include <math.h>

namespace cgr = cooperative_groups;

#define NB 4
#define NC 12
#define NM 2
#define NN 320
#define NHW (NN*NN)
#define NBC (NB*NC)
#define CG_TOL 1e-6f
#define NITER 10
#define PBLK 400   // |r|^2 partial slots per batch
#define QBLK 320   // pq partials per batch (one per h-row)
#define CPG 3      // coils per group
#define NG  4      // groups
#define TROW 4     // tile rows per block (1 per wave)
#define LSTR (NN + 2)

#define TWO_PI_F 6.28318530717958647692f

typedef float2 c32;

__device__ __forceinline__ c32 cmul(c32 a, c32 b){ return make_float2(a.x*b.x - a.y*b.y, a.x*b.y + a.y*b.x); }
__device__ __forceinline__ c32 cmulj(c32 a, c32 b){ return make_float2(a.x*b.x + a.y*b.y, a.x*b.y - a.y*b.x); } // conj(a)*b
__device__ __forceinline__ c32 cadd(c32 a, c32 b){ return make_float2(a.x+b.x, a.y+b.y); }
__device__ __forceinline__ c32 csub(c32 a, c32 b){ return make_float2(a.x-b.x, a.y-b.y); }
__device__ __forceinline__ c32 cscale(c32 a, float s){ return make_float2(a.x*s, a.y*s); }

template<bool CONJ>
__device__ __forceinline__ c32 twmul(c32 a, c32 t){
  return CONJ ? make_float2(a.x*t.x + a.y*t.y, a.y*t.x - a.x*t.y)
              : make_float2(a.x*t.x - a.y*t.y, a.y*t.x + a.x*t.y);
}

__device__ __forceinline__ float wave_reduce_f(float v) {
  #pragma unroll
  for (int off = 32; off >= 1; off >>= 1) v += __shfl_xor(v, off, 64);
  return v;
}
__device__ __forceinline__ c32 wave_reduce_c(c32 v) {
  #pragma unroll
  for (int off = 32; off >= 1; off >>= 1) {
    v.x += __shfl_xor(v.x, off, 64);
    v.y += __shfl_xor(v.y, off, 64);
  }
  return v;
}

template<bool FWD>
__device__ __forceinline__ void radix5(c32 V[5]) {
  constexpr float C1 = 0.30901699437494745f;
  constexpr float S1 = 0.9510565162951535f;
  constexpr float C2 = -0.8090169943749475f;
  constexpr float S2 = 0.5877852522924731f;
  constexpr float sg = FWD ? -1.f : 1.f;
  const c32 w1 = make_float2(C1,  sg*S1);
  const c32 w2 = make_float2(C2,  sg*S2);
  const c32 w3 = make_float2(C2, -sg*S2);
  const c32 w4 = make_float2(C1, -sg*S1);
  c32 v0=V[0], v1=V[1], v2=V[2], v3=V[3], v4=V[4];
  V[0] = cadd(cadd(v0, v1), cadd(cadd(v2, v3), v4));
  V[1] = cadd(v0, cadd(cadd(cmul(v1,w1), cmul(v2,w2)), cadd(cmul(v3,w3), cmul(v4,w4))));
  V[2] = cadd(v0, cadd(cadd(cmul(v1,w2), cmul(v2,w4)), cadd(cmul(v3,w1), cmul(v4,w3))));
  V[3] = cadd(v0, cadd(cadd(cmul(v1,w3), cmul(v2,w1)), cadd(cmul(v3,w4), cmul(v4,w2))));
  V[4] = cadd(v0, cadd(cadd(cmul(v1,w4), cmul(v2,w3)), cadd(cmul(v3,w2), cmul(v4,w1))));
}

// 320-pt FFT: A[j]=x[lane+64j] (natural) -> A[k]=X[k+5*rev6(lane)] (scrambled).
template<bool FWD>
__device__ __forceinline__ void fft320_one(c32 A[5], const c32 ct[4], const c32 tw[6], int lane)
{
  radix5<FWD>(A);
  #pragma unroll
  for (int k = 1; k < 5; ++k) A[k] = twmul<FWD>(A[k], ct[k-1]);
  #pragma unroll
  for (int s = 0; s < 6; ++s) {
    const int m = 32 >> s;
    const c32 w = tw[s];
    const bool up = (lane & m) != 0;
    c32 o[5];
    #pragma unroll
    for (int k = 0; k < 5; ++k) { o[k].x = __shfl_xor(A[k].x, m, 64); o[k].y = __shfl_xor(A[k].y, m, 64); }
    #pragma unroll
    for (int k = 0; k < 5; ++k) {
      c32 lo = cadd(A[k], o[k]);
      c32 hi = twmul<FWD>(csub(o[k], A[k]), w);
      A[k] = up ? hi : lo;
    }
  }
}

// Inverse DIT consuming SCRAMBLED input: A[k]=X[k+5*rev6(lane)] -> A[j]=320*x[lane+64j].
__device__ __forceinline__ void ifft320_dit(c32 A[5], const c32 ct[4], const c32 tw[6], int lane)
{
  #pragma unroll
  for (int s = 5; s >= 0; --s) {
    const int m = 32 >> s;
    const c32 w = tw[s];
    const bool up = (lane & m) != 0;
    #pragma unroll
    for (int k = 0; k < 5; ++k) {
      c32 t = up ? twmul<false>(A[k], w) : A[k];
      c32 o; o.x = __shfl_xor(t.x, m, 64); o.y = __shfl_xor(t.y, m, 64);
      A[k] = up ? csub(o, t) : cadd(t, o);
    }
  }
  #pragma unroll
  for (int k = 1; k < 5; ++k) A[k] = twmul<false>(A[k], ct[k-1]);
  radix5<false>(A);
}

__device__ __forceinline__ float sel4(const float a[4], int i) {
  float r = a[0];
  r = (i == 1) ? a[1] : r;
  r = (i == 2) ? a[2] : r;
  r = (i == 3) ? a[3] : r;
  return r;
}

// ===== the whole DataProxCG layer as one cooperative kernel =====
__global__ __launch_bounds__(256, 3)
void cg_all(const c32* __restrict__ z, const c32* __restrict__ y,
            const c32* __restrict__ sm, const float* __restrict__ mk,
            const float* __restrict__ lam,
            c32* __restrict__ x, c32* __restrict__ buf1, c32* __restrict__ buf2,
            c32* __restrict__ rv, c32* __restrict__ pvA, c32* __restrict__ pvB,
            c32* __restrict__ qv, c32* __restrict__ pqpart, float* __restrict__ part1)
{
  cgr::grid_group grid = cgr::this_grid();
  __shared__ c32 tile[TROW][LSTR];
  __shared__ float sredf[8];
  __shared__ c32 sqq[4];
  const int tid = threadIdx.x, lane = tid & 63, wv = tid >> 6;
  const int bid = blockIdx.x;
  const int nblk = gridDim.x;
  const float lamv = lam[0];

  // per-thread twiddles, computed once for the whole layer
  c32 ct[4], tw[6];
  #pragma unroll
  for (int k = 0; k < 4; ++k) {
    float s, c; sincosf(TWO_PI_F * (float)((k + 1) * lane) / 320.f, &s, &c);
    ct[k] = make_float2(c, s);
  }
  #pragma unroll
  for (int s6 = 0; s6 < 6; ++s6) {
    const int m = 32 >> s6;
    float s, c; sincosf(TWO_PI_F * (float)((lane & (m - 1)) << s6) / 64.f, &s, &c);
    tw[s6] = make_float2(c, s);
  }
  const int rv6 = __brev((unsigned)lane) >> 26;

  // ---- S1: (y*mask) IDFT along k_w, transposed write buf2[bc][w][kh] ----
  for (int u = bid; u < 1280; u += nblk) {
    const int xu = u % 80, by = u / 80;
    const int b = by >> 2, g = by & 3;
    const int r0 = xu * TROW, row = r0 + wv;      // row = kh index
    for (int cc = 0; cc < CPG; ++cc) {
      const int bc = b*NC + g*CPG + cc;
      c32 A[5];
      #pragma unroll
      for (int j = 0; j < 5; ++j) {
        const size_t idx = ((size_t)bc * NN + row) * NN + lane + 64*j;
        A[j] = cscale(y[idx], mk[idx]);
      }
      fft320_one<false>(A, ct, tw, lane);
      __syncthreads();
      #pragma unroll
      for (int k = 0; k < 5; ++k) tile[wv][k + 5*rv6] = A[k];
      __syncthreads();
      #pragma unroll
      for (int it5 = 0; it5 < 5; ++it5) {
        const int idx = it5 * 256 + tid, u2 = idx >> 2, d = idx & 3;
        buf2[((size_t)bc * NN + u2) * NN + (r0 + d)] = tile[d][u2];   // [bc][w][kh]
      }
    }
  }
  grid.sync();

  // ---- S2: IDFT along k_h, natural write buf1[bc][h][w] ----
  for (int u = bid; u < 1280; u += nblk) {
    const int xu = u % 80, by = u / 80;
    const int b = by >> 2, g = by & 3;
    const int r0 = xu * TROW, w = r0 + wv;        // w index
    for (int cc = 0; cc < CPG; ++cc) {
      const int bc = b*NC + g*CPG + cc;
      c32 A[5];
      #pragma unroll
      for (int j = 0; j < 5; ++j)
        A[j] = buf2[((size_t)bc * NN + w) * NN + lane + 64*j];
      fft320_one<false>(A, ct, tw, lane);         // kh -> scrambled h
      __syncthreads();
      #pragma unroll
      for (int k = 0; k < 5; ++k) tile[wv][k + 5*rv6] = A[k];
      __syncthreads();
      #pragma unroll
      for (int it5 = 0; it5 < 5; ++it5) {
        const int idx = it5 * 256 + tid, h = idx >> 2, d = idx & 3;
        buf1[((size_t)bc * NN + h) * NN + (r0 + d)] = tile[d][h];     // [bc][h][w]
      }
    }
  }
  grid.sync();

  // ---- S3: x0 = (lam/NN)*sum_c conj(sm)*img + z ; x=0, r=p=x0 ; |x0|^2 partials ----
  for (int u = bid; u < NB * PBLK; u += nblk) {
    const int b = u / PBLK, blk = u % PBLK;
    const int hw = blk * 256 + tid;
    const float l0 = lamv * (1.f / (float)NN);
    c32 a0 = make_float2(0.f,0.f), a1 = make_float2(0.f,0.f);
    for (int c = 0; c < NC; ++c) {
      c32 iv = buf1[(size_t)(b*NC + c) * NHW + hw];
      c32 s0 = sm[(size_t)((b*NC + c)*NM + 0) * NHW + hw];
      c32 s1 = sm[(size_t)((b*NC + c)*NM + 1) * NHW + hw];
      a0 = cadd(a0, cmulj(s0, iv));
      a1 = cadd(a1, cmulj(s1, iv));
    }
    const size_t i0 = (size_t)(b*NM + 0) * NHW + hw;
    const size_t i1 = (size_t)(b*NM + 1) * NHW + hw;
    c32 x00 = cadd(cscale(a0, l0), z[i0]);
    c32 x01 = cadd(cscale(a1, l0), z[i1]);
    x[i0] = make_float2(0.f,0.f); x[i1] = make_float2(0.f,0.f);
    rv[i0] = x00; rv[i1] = x01;
    pvA[i0] = x00; pvA[i1] = x01;
    float accf = x00.x*x00.x + x00.y*x00.y + x01.x*x01.x + x01.y*x01.y;
    accf = wave_reduce_f(accf);
    __syncthreads();
    if (lane == 0) sredf[wv] = accf;
    __syncthreads();
    if (tid == 0) part1[b*PBLK + blk] = sredf[0]+sredf[1]+sredf[2]+sredf[3];
  }
  grid.sync();

  // ---- CG loop: 4 phases per iteration, zero-cost dead iterations ----
  float rrP[4], rrC[4], xx[4];
  for (int it = 0; it < NITER; ++it) {
    // head: every block redundantly reduces part1 (L2-hot) -> rr_cur (bit-identical)
    {
      float s = 0.f;
      for (int j = lane; j < PBLK; j += 64) s += part1[wv*PBLK + j];   // wave wv <-> batch wv
      s = wave_reduce_f(s);
      __syncthreads();
      if (lane == 0) sredf[wv] = s;
      __syncthreads();
    }
    #pragma unroll
    for (int bb = 0; bb < 4; ++bb) rrC[bb] = sredf[bb];
    if (it == 0) {
      #pragma unroll
      for (int bb = 0; bb < 4; ++bb) xx[bb] = rrC[bb];
    } else {
      // reference: active = min(rr/x0x0) > tol (always true at it=0 since rr0/x0x0 = 1)
      const float mn = fminf(fminf(rrC[0]/xx[0], rrC[1]/xx[1]), fminf(rrC[2]/xx[2], rrC[3]/xx[3]));
      if (!(mn > CG_TOL)) break;    // uniform across grid (same data, same float ops)
    }

    c32* pin  = (it & 1) ? pvA : pvB;
    c32* pout = (it & 1) ? pvB : pvA;
    const bool upd = (it != 0);

    // phase A: p_new = r + beta*p_prev; coil-combine; FFT_w; write buf2[bc][kw][h]
    for (int u = bid; u < 1280; u += nblk) {
      const int xu = u % 80, by = u / 80;
      const int b = by >> 2, g = by & 3;
      const int r0 = xu * TROW, row = r0 + wv;    // image h row
      const float beta = upd ? sel4(rrC, b) / sel4(rrP, b) : 0.f;
      const size_t m0 = (size_t)(b*NM + 0) * NHW, m1 = (size_t)(b*NM + 1) * NHW;
      c32 p0[5], p1[5];
      #pragma unroll
      for (int j = 0; j < 5; ++j) {
        const size_t h = (size_t)row * NN + lane + 64*j;
        c32 r0v = rv[m0 + h], r1v = rv[m1 + h];
        if (upd) {
          p0[j] = cadd(r0v, cscale(pin[m0 + h], beta));
          p1[j] = cadd(r1v, cscale(pin[m1 + h], beta));
          if (g == 0) { pout[m0 + h] = p0[j]; pout[m1 + h] = p1[j]; }
        } else { p0[j] = r0v; p1[j] = r1v; }
      }
      for (int cc = 0; cc < CPG; ++cc) {
        const int c = g * CPG + cc;
        const size_t s0o = (size_t)((b*NC + c)*NM + 0) * NHW, s1o = (size_t)((b*NC + c)*NM + 1) * NHW;
        c32 A[5];
        #pragma unroll
        for (int j = 0; j < 5; ++j) {
          const size_t h = (size_t)row * NN + lane + 64*j;
          A[j] = cadd(cmul(p0[j], sm[s0o + h]), cmul(p1[j], sm[s1o + h]));
        }
        fft320_one<true>(A, ct, tw, lane);
        __syncthreads();
        #pragma unroll
        for (int k = 0; k < 5; ++k) tile[wv][k + 5*rv6] = A[k];
        __syncthreads();
        #pragma unroll
        for (int it5 = 0; it5 < 5; ++it5) {
          const int idx = it5 * 256 + tid, u2 = idx >> 2, d = idx & 3;
          buf2[(size_t)(b*NC + c) * NHW + (size_t)u2 * NN + (r0 + d)] = tile[d][u2];  // [bc][kw][h]
        }
      }
    }
    grid.sync();

    // phase B: FFT_h -> mask (scrambled) -> DIT-IFFT_h -> write buf1[bc][h][kw]
    for (int u = bid; u < 1280; u += nblk) {
      const int xu = u % 80, by = u / 80;
      const int b = by >> 2, g = by & 3;
      const int r0 = xu * TROW, row = r0 + wv;    // k_w row
      for (int cc = 0; cc < CPG; ++cc) {
        const int bc = b*NC + g*CPG + cc;
        c32 A[5];
        #pragma unroll
        for (int j = 0; j < 5; ++j)
          A[j] = buf2[((size_t)bc * NN + row) * NN + lane + 64*j];
        fft320_one<true>(A, ct, tw, lane);        // h -> scrambled kh
        #pragma unroll
        for (int k = 0; k < 5; ++k) {
          const int kh = k + 5*rv6;
          A[k] = cscale(A[k], mk[(size_t)bc * NHW + (size_t)kh * NN + row]);
        }
        ifft320_dit(A, ct, tw, lane);             // scrambled kh -> natural h
        __syncthreads();
        #pragma unroll
        for (int j = 0; j < 5; ++j) tile[wv][lane + 64*j] = A[j];
        __syncthreads();
        #pragma unroll
        for (int it5 = 0; it5 < 5; ++it5) {
          const int idx = it5 * 256 + tid, u2 = idx >> 2, d = idx & 3;
          buf1[(size_t)bc * NHW + (size_t)u2 * NN + (r0 + d)] = tile[d][u2];  // [bc][h][kw]
        }
      }
    }
    grid.sync();

    // phase C: IFFT_w + coil-combine + q = (lam/NHW)*AT + p ; pq partials
    for (int u = bid; u < NB * QBLK; u += nblk) {
      const int b = u / QBLK, h = u % QBLK;
      __syncthreads();   // tile reuse across units/phases
      const float lq = lamv * (1.f / (float)NHW);
      const size_t rowoff = (size_t)h * NN + lane;
      c32 acc0[5], acc1[5];
      #pragma unroll
      for (int j = 0; j < 5; ++j) { acc0[j] = make_float2(0.f,0.f); acc1[j] = make_float2(0.f,0.f); }
      for (int cc = 0; cc < CPG; ++cc) {
        const int c = wv * CPG + cc;
        const size_t ib  = (size_t)(b*NC + c) * NHW + rowoff;
        const size_t is0 = (size_t)((b*NC + c)*NM + 0) * NHW + rowoff;
        const size_t is1 = (size_t)((b*NC + c)*NM + 1) * NHW + rowoff;
        c32 A[5], S0[5], S1[5];
        #pragma unroll
        for (int j = 0; j < 5; ++j) {
          A[j] = buf1[ib + 64*j]; S0[j] = sm[is0 + 64*j]; S1[j] = sm[is1 + 64*j];
        }
        fft320_one<false>(A, ct, tw, lane);       // natural kw -> scrambled w
        #pragma unroll
        for (int k = 0; k < 5; ++k) tile[wv][k + 5*rv6] = A[k];   // wave-local unscramble
        #pragma unroll
        for (int j = 0; j < 5; ++j) {
          c32 v = tile[wv][lane + 64*j];
          acc0[j] = cadd(acc0[j], cmulj(S0[j], v));
          acc1[j] = cadd(acc1[j], cmulj(S1[j], v));
        }
      }
      // cross-wave reduce through flattened tile (4*LSTR = 1288 c32 >= 1280)
      c32* red = &tile[0][0];
      __syncthreads();
      if (wv >= 2) {
        const int base = (wv - 2) * 640;
        #pragma unroll
        for (int j = 0; j < 5; ++j) {
          red[base + j*64 + lane] = acc0[j];
          red[base + 320 + j*64 + lane] = acc1[j];
        }
      }
      __syncthreads();
      if (wv < 2) {
        const int base = wv * 640;
        #pragma unroll
        for (int j = 0; j < 5; ++j) {
          acc0[j] = cadd(acc0[j], red[base + j*64 + lane]);
          acc1[j] = cadd(acc1[j], red[base + 320 + j*64 + lane]);
        }
      }
      __syncthreads();
      if (wv == 1) {
        #pragma unroll
        for (int j = 0; j < 5; ++j) {
          red[j*64 + lane] = acc0[j];
          red[320 + j*64 + lane] = acc1[j];
        }
      }
      __syncthreads();
      if (wv == 0) {
        const size_t i0 = (size_t)(b*NM + 0) * NHW + rowoff;
        const size_t i1 = (size_t)(b*NM + 1) * NHW + rowoff;
        c32 pqs = make_float2(0.f, 0.f);
        #pragma unroll
        for (int j = 0; j < 5; ++j) {
          acc0[j] = cadd(acc0[j], red[j*64 + lane]);
          acc1[j] = cadd(acc1[j], red[320 + j*64 + lane]);
          c32 p0 = pout[i0 + 64*j], p1 = pout[i1 + 64*j];
          c32 q0 = cadd(cscale(acc0[j], lq), p0);
          c32 q1 = cadd(cscale(acc1[j], lq), p1);
          qv[i0 + 64*j] = q0; qv[i1 + 64*j] = q1;
          pqs = cadd(pqs, cadd(cmulj(q0, p0), cmulj(q1, p1)));
        }
        pqs = wave_reduce_c(pqs);
        if (lane == 0) pqpart[b*QBLK + h] = pqs;
      }
    }
    grid.sync();

    // phase D: reduce pq -> alpha; x += a p; r -= a q; |r|^2 partials
    for (int u = bid; u < NB * PBLK; u += nblk) {
      const int b = u / PBLK, blk = u % PBLK;
      __syncthreads();   // sqq/sredf reuse across units
      c32 s = make_float2(0.f, 0.f);
      for (int j = tid; j < QBLK; j += 256) s = cadd(s, pqpart[b*QBLK + j]);
      s = wave_reduce_c(s);
      if (lane == 0) sqq[wv] = s;
      __syncthreads();
      const c32 pqv = cadd(cadd(sqq[0], sqq[1]), cadd(sqq[2], sqq[3]));
      const float rrv = sel4(rrC, b);
      const float den = pqv.x*pqv.x + pqv.y*pqv.y;
      const c32 alpha = make_float2(rrv * pqv.x / den, -rrv * pqv.y / den);
      const int hw = blk * 256 + tid;
      float acc = 0.f;
      #pragma unroll
      for (int m = 0; m < NM; ++m) {
        const size_t idx = (size_t)(b*NM + m) * NHW + hw;
        c32 pe = pout[idx], qe = qv[idx];
        c32 xe = cadd(x[idx], cmul(alpha, pe));
        c32 re = csub(rv[idx], cmul(alpha, qe));
        x[idx] = xe; rv[idx] = re;
        acc += re.x*re.x + re.y*re.y;
      }
      acc = wave_reduce_f(acc);
      if (lane == 0) sredf[wv] = acc;
      __syncthreads();
      if (tid == 0) part1[b*PBLK + blk] = sredf[0]+sredf[1]+sredf[2]+sredf[3];
    }
    grid.sync();

    #pragma unroll
    for (int bb = 0; bb < 4; ++bb) rrP[bb] = rrC[bb];
  }
}

extern "C" void kernel_launch(void* const* d_in, const int* in_sizes, int n_in,
                              void* d_out, int out_size, void* d_ws, size_t ws_size,
                              hipStream_t stream)
{
  const c32*  z   = (const c32*)d_in[0];
  const c32*  y   = (const c32*)d_in[1];
  const c32*  sm  = (const c32*)d_in[2];
  const float* mk = (const float*)d_in[3];
  const float* lam= (const float*)d_in[4];
  c32* x = (c32*)d_out;

  char* base = (char*)d_ws;
  size_t off = 0;
  auto walloc = [&](size_t bytes) -> void* {
    void* ptr = base + off;
    off += (bytes + 255) & ~(size_t)255;
    return ptr;
  };
  c32* buf1   = (c32*)walloc((size_t)NBC * NHW * sizeof(c32));
  c32* buf2   = (c32*)walloc((size_t)NBC * NHW * sizeof(c32));
  c32* rv     = (c32*)walloc((size_t)NB * NM * NHW * sizeof(c32));
  c32* pvA    = (c32*)walloc((size_t)NB * NM * NHW * sizeof(c32));
  c32* pvB    = (c32*)walloc((size_t)NB * NM * NHW * sizeof(c32));
  c32* qv     = (c32*)walloc((size_t)NB * NM * NHW * sizeof(c32));
  c32* pqpart = (c32*)walloc((size_t)NB * QBLK * sizeof(c32));
  float* part1= (float*)walloc((size_t)NB * PBLK * sizeof(float));
  (void)ws_size; (void)in_sizes; (void)n_in; (void)out_size;

  // occupancy-derived cooperative grid: never exceeds what the HW can co-schedule
  int dev = 0;
  (void)hipGetDevice(&dev);
  int cus = 0;
  if (hipDeviceGetAttribute(&cus, hipDeviceAttributeMultiprocessorCount, dev) != hipSuccess || cus <= 0)
    cus = 256;
  int perCU = 0;
  if (hipOccupancyMaxActiveBlocksPerMultiprocessor(&perCU, (const void*)cg_all, 256, 0) != hipSuccess || perCU < 1)
    perCU = 1;
  long long nblk_ll = (long long)cus * (long long)perCU;
  int nblk = (nblk_ll > 1024) ? 1024 : (int)nblk_ll;

  void* args[] = { (void*)&z, (void*)&y, (void*)&sm, (void*)&mk, (void*)&lam,
                   (void*)&x, (void*)&buf1, (void*)&buf2, (void*)&rv,
                   (void*)&pvA, (void*)&pvB, (void*)&qv, (void*)&pqpart, (void*)&part1 };
  hipLaunchCooperativeKernel((const void*)cg_all, dim3(nblk), dim3(256), args, 0, stream);
}

// Round 11
// 377.284 us; speedup vs baseline: 2.3549x; 2.3549x over previous
//
#include <hip/hip_runtime.h>
#include <math.h>

#define NB 4
#define NC 12
#define NM 2
#define NN 320
#define NHW (NN*NN)
#define NBC (NB*NC)
#define CG_TOL 1e-6f
#define NITER 10
#define PBLK 400   // |r|^2 partial slots per batch (update1 grid x)
#define QBLK 320   // pq partials per batch (one per h-row)
#define QROW 4     // ifft_q LDS rows (1 per wave)
#define LSTR (NN + 2)

#define TWO_PI_F 6.28318530717958647692f

typedef float2 c32;

__device__ __forceinline__ c32 cmul(c32 a, c32 b){ return make_float2(a.x*b.x - a.y*b.y, a.x*b.y + a.y*b.x); }
__device__ __forceinline__ c32 cmulj(c32 a, c32 b){ return make_float2(a.x*b.x + a.y*b.y, a.x*b.y - a.y*b.x); } // conj(a)*b
__device__ __forceinline__ c32 cadd(c32 a, c32 b){ return make_float2(a.x+b.x, a.y+b.y); }
__device__ __forceinline__ c32 csub(c32 a, c32 b){ return make_float2(a.x-b.x, a.y-b.y); }
__device__ __forceinline__ c32 cscale(c32 a, float s){ return make_float2(a.x*s, a.y*s); }

// multiply a by (CONJ ? conj(t) : t) — fwd/inv share one twiddle table
template<bool CONJ>
__device__ __forceinline__ c32 twmul(c32 a, c32 t){
  return CONJ ? make_float2(a.x*t.x + a.y*t.y, a.y*t.x - a.x*t.y)
              : make_float2(a.x*t.x - a.y*t.y, a.y*t.x + a.x*t.y);
}

__device__ __forceinline__ float wave_reduce_f(float v) {
  #pragma unroll
  for (int off = 32; off >= 1; off >>= 1) v += __shfl_xor(v, off, 64);
  return v;
}
__device__ __forceinline__ c32 wave_reduce_c(c32 v) {
  #pragma unroll
  for (int off = 32; off >= 1; off >>= 1) {
    v.x += __shfl_xor(v.x, off, 64);
    v.y += __shfl_xor(v.y, off, 64);
  }
  return v;
}

// T320[j] = cis(2*pi*j/320), j=0..255 ; T64[k] = cis(2*pi*k/64), k=0..31.
__global__ __launch_bounds__(256)
void twiddle_init(c32* __restrict__ T320, c32* __restrict__ T64)
{
  const int t = threadIdx.x;
  {
    float s, c; sincosf(TWO_PI_F * (float)t / 320.f, &s, &c);
    T320[t] = make_float2(c, s);
  }
  if (t < 32) {
    float s, c; sincosf(TWO_PI_F * (float)t / 64.f, &s, &c);
    T64[t] = make_float2(c, s);
  }
}

template<bool FWD>
__device__ __forceinline__ void radix5(c32 V[5]) {
  constexpr float C1 = 0.30901699437494745f;
  constexpr float S1 = 0.9510565162951535f;
  constexpr float C2 = -0.8090169943749475f;
  constexpr float S2 = 0.5877852522924731f;
  constexpr float sg = FWD ? -1.f : 1.f;
  const c32 w1 = make_float2(C1,  sg*S1);
  const c32 w2 = make_float2(C2,  sg*S2);
  const c32 w3 = make_float2(C2, -sg*S2);
  const c32 w4 = make_float2(C1, -sg*S1);
  c32 v0=V[0], v1=V[1], v2=V[2], v3=V[3], v4=V[4];
  V[0] = cadd(cadd(v0, v1), cadd(cadd(v2, v3), v4));
  V[1] = cadd(v0, cadd(cadd(cmul(v1,w1), cmul(v2,w2)), cadd(cmul(v3,w3), cmul(v4,w4))));
  V[2] = cadd(v0, cadd(cadd(cmul(v1,w2), cmul(v2,w4)), cadd(cmul(v3,w1), cmul(v4,w3))));
  V[3] = cadd(v0, cadd(cadd(cmul(v1,w3), cmul(v2,w1)), cadd(cmul(v3,w4), cmul(v4,w2))));
  V[4] = cadd(v0, cadd(cadd(cmul(v1,w4), cmul(v2,w3)), cadd(cmul(v3,w2), cmul(v4,w1))));
}

// Two interleaved 320-pt FFTs (rows A,B): A[j]=x[lane+64j] -> A[k]=X[k+5*rev6(lane)].
template<bool FWD>
__device__ __forceinline__ void fft320_x2(c32 A[5], c32 B[5],
                                          const c32 ct[4], const c32 tw[6], int lane)
{
  radix5<FWD>(A);
  radix5<FWD>(B);
  #pragma unroll
  for (int k = 1; k < 5; ++k) {
    A[k] = twmul<FWD>(A[k], ct[k-1]);
    B[k] = twmul<FWD>(B[k], ct[k-1]);
  }
  #pragma unroll
  for (int s = 0; s < 6; ++s) {
    const int m = 32 >> s;
    const c32 w = tw[s];
    const bool up = (lane & m) != 0;
    c32 oA[5], oB[5];
    #pragma unroll
    for (int k = 0; k < 5; ++k) { oA[k].x = __shfl_xor(A[k].x, m, 64); oA[k].y = __shfl_xor(A[k].y, m, 64); }
    #pragma unroll
    for (int k = 0; k < 5; ++k) { oB[k].x = __shfl_xor(B[k].x, m, 64); oB[k].y = __shfl_xor(B[k].y, m, 64); }
    #pragma unroll
    for (int k = 0; k < 5; ++k) {
      c32 loA = cadd(A[k], oA[k]);
      c32 hiA = twmul<FWD>(csub(oA[k], A[k]), w);
      A[k] = up ? hiA : loA;
      c32 loB = cadd(B[k], oB[k]);
      c32 hiB = twmul<FWD>(csub(oB[k], B[k]), w);
      B[k] = up ? hiB : loB;
    }
  }
}

// One 320-pt FFT per wave (used by ifft_q).
template<bool FWD>
__device__ __forceinline__ void fft320_one(c32 A[5], const c32 ct[4], const c32 tw[6], int lane)
{
  radix5<FWD>(A);
  #pragma unroll
  for (int k = 1; k < 5; ++k) A[k] = twmul<FWD>(A[k], ct[k-1]);
  #pragma unroll
  for (int s = 0; s < 6; ++s) {
    const int m = 32 >> s;
    const c32 w = tw[s];
    const bool up = (lane & m) != 0;
    c32 o[5];
    #pragma unroll
    for (int k = 0; k < 5; ++k) { o[k].x = __shfl_xor(A[k].x, m, 64); o[k].y = __shfl_xor(A[k].y, m, 64); }
    #pragma unroll
    for (int k = 0; k < 5; ++k) {
      c32 lo = cadd(A[k], o[k]);
      c32 hi = twmul<FWD>(csub(o[k], A[k]), w);
      A[k] = up ? hi : lo;
    }
  }
}

#define LOAD_TWIDDLES \
  c32 ct[4], tw[6]; \
  _Pragma("unroll") for (int k_ = 0; k_ < 4; ++k_) ct[k_] = T320[(k_ + 1) * lane]; \
  _Pragma("unroll") for (int s_ = 0; s_ < 6; ++s_) tw[s_] = T64[(lane & ((32 >> s_) - 1)) << s_];

// Batched 1D FFT over contiguous dim of (NBC, NN, NN), transposed write (R4 body).
// MASK_IN: multiply input by mask.
template<bool FWD, bool MASK_IN>
__global__ __launch_bounds__(256)
void fft_pass(const c32* __restrict__ in, c32* __restrict__ out,
              const float* __restrict__ mask,
              const c32* __restrict__ T320, const c32* __restrict__ T64)
{
  __shared__ c32 tile[8][LSTR];
  const int tid = threadIdx.x, lane = tid & 63, wv = tid >> 6;
  const int bc = blockIdx.y, r0 = blockIdx.x * 8;
  LOAD_TWIDDLES
  const int rv6 = __brev((unsigned)lane) >> 26;
  const int rA = r0 + wv*2, rB = rA + 1;
  c32 A[5], B[5];
  #pragma unroll
  for (int j = 0; j < 5; ++j) {
    const size_t iA = ((size_t)bc * NN + rA) * NN + lane + 64*j;
    const size_t iB = ((size_t)bc * NN + rB) * NN + lane + 64*j;
    A[j] = in[iA]; B[j] = in[iB];
    if constexpr (MASK_IN) { A[j] = cscale(A[j], mask[iA]); B[j] = cscale(B[j], mask[iB]); }
  }
  fft320_x2<FWD>(A, B, ct, tw, lane);
  #pragma unroll
  for (int k = 0; k < 5; ++k) {
    tile[wv*2    ][k + 5*rv6] = A[k];
    tile[wv*2 + 1][k + 5*rv6] = B[k];
  }
  __syncthreads();
  #pragma unroll
  for (int it = 0; it < 10; ++it) {
    const int idx = it * 256 + tid, u = idx >> 3, d = idx & 7;
    out[((size_t)bc * NN + u) * NN + (r0 + d)] = tile[d][u];
  }
}

// x0 = (lam/NN)*sum_c conj(sm)*img + z ; x=0, r=p=x0 ; |x0|^2 partials (R4 body)
__global__ __launch_bounds__(256)
void init_combine(const c32* __restrict__ img, const c32* __restrict__ smaps,
                  const c32* __restrict__ z, c32* __restrict__ x,
                  c32* __restrict__ r, c32* __restrict__ p,
                  const float* __restrict__ lam, float* __restrict__ part)
{
  const int b  = blockIdx.y;
  const int hw = blockIdx.x * 256 + threadIdx.x;
  const float l0 = lam[0] * (1.f / (float)NN);
  c32 a0 = make_float2(0.f,0.f), a1 = make_float2(0.f,0.f);
  #pragma unroll
  for (int c = 0; c < NC; ++c) {
    c32 iv = img[(size_t)(b*NC + c) * NHW + hw];
    c32 s0 = smaps[(size_t)((b*NC + c)*NM + 0) * NHW + hw];
    c32 s1 = smaps[(size_t)((b*NC + c)*NM + 1) * NHW + hw];
    a0 = cadd(a0, cmulj(s0, iv));
    a1 = cadd(a1, cmulj(s1, iv));
  }
  const size_t i0 = (size_t)(b*NM + 0) * NHW + hw;
  const size_t i1 = (size_t)(b*NM + 1) * NHW + hw;
  c32 x00 = cadd(cscale(a0, l0), z[i0]);
  c32 x01 = cadd(cscale(a1, l0), z[i1]);
  x[i0] = make_float2(0.f,0.f); x[i1] = make_float2(0.f,0.f);
  r[i0] = x00; r[i1] = x01;
  p[i0] = x00; p[i1] = x01;
  float acc = x00.x*x00.x + x00.y*x00.y + x01.x*x01.x + x01.y*x01.y;
  acc = wave_reduce_f(acc);
  __shared__ float sred[4];
  const int lane = threadIdx.x & 63, wv = threadIdx.x >> 6;
  if (lane == 0) sred[wv] = acc;
  __syncthreads();
  if (threadIdx.x == 0) part[b*PBLK + blockIdx.x] = sred[0]+sred[1]+sred[2]+sred[3];
}

// Per-iter kernel 1 (R4 body + R7 head): self-reduce part1 -> rr_it, flag, beta;
// publish rr[it]/flags[it]; p_new = r + beta*p_prev; coil-combine; FFT_w; transposed write.
__global__ __launch_bounds__(256)
void fft_comb(c32* __restrict__ out, const c32* __restrict__ pin,
              const c32* __restrict__ rres, c32* __restrict__ pout,
              const c32* __restrict__ smaps,
              float* __restrict__ rr, float* __restrict__ flags,
              const float* __restrict__ part1, const int it,
              const c32* __restrict__ T320, const c32* __restrict__ T64)
{
  __shared__ c32 tile[8][LSTR];
  __shared__ float sstat[NB];
  const int tid = threadIdx.x, lane = tid & 63, wv = tid >> 6;
  const int bc = blockIdx.y, r0 = blockIdx.x * 8;
  const int b = bc / NC, c = bc - b * NC;
  // head: waves 0..3 reduce batch wv's partials (L2-hot, 1.6 KB each)
  {
    float s = 0.f;
    for (int j = lane; j < PBLK; j += 64) s += part1[wv*PBLK + j];
    s = wave_reduce_f(s);
    if (lane == 0) sstat[wv] = s;
  }
  __syncthreads();
  float flag;
  if (it == 0) flag = 1.f;
  else {
    float mn = 1e30f;
    #pragma unroll
    for (int bb = 0; bb < NB; ++bb) mn = fminf(mn, sstat[bb] / rr[bb]);  // rr[0..3] = rr_0 = x0x0
    flag = (mn > CG_TOL) ? 1.f : 0.f;
  }
  if (tid < NB) rr[it*NB + tid] = sstat[tid];   // identical redundant writes
  if (tid == 0) flags[it] = flag;
  if (it != 0 && flag == 0.f) return;
  const float beta = (it != 0) ? sstat[b] / rr[(it-1)*NB + b] : 0.f;
  const bool upd = (it != 0);

  LOAD_TWIDDLES
  const int rv6 = __brev((unsigned)lane) >> 26;
  const int rA = r0 + wv*2, rB = rA + 1;
  const size_t m0 = (size_t)(b*NM + 0) * NHW, m1 = (size_t)(b*NM + 1) * NHW;
  const size_t s0o = (size_t)((b*NC + c)*NM + 0) * NHW, s1o = (size_t)((b*NC + c)*NM + 1) * NHW;
  c32 A[5], B[5];
  #pragma unroll
  for (int j = 0; j < 5; ++j) {
    const size_t hA = (size_t)rA * NN + lane + 64*j;
    const size_t hB = (size_t)rB * NN + lane + 64*j;
    c32 r0A = rres[m0 + hA], r1A = rres[m1 + hA];
    c32 r0B = rres[m0 + hB], r1B = rres[m1 + hB];
    c32 p0A, p1A, p0B, p1B;
    if (upd) {
      p0A = cadd(r0A, cscale(pin[m0 + hA], beta));
      p1A = cadd(r1A, cscale(pin[m1 + hA], beta));
      p0B = cadd(r0B, cscale(pin[m0 + hB], beta));
      p1B = cadd(r1B, cscale(pin[m1 + hB], beta));
      if (c == 0) {
        pout[m0 + hA] = p0A; pout[m1 + hA] = p1A;
        pout[m0 + hB] = p0B; pout[m1 + hB] = p1B;
      }
    } else {
      p0A = r0A; p1A = r1A; p0B = r0B; p1B = r1B;   // iter 0: p = r = x0
    }
    A[j] = cadd(cmul(p0A, smaps[s0o + hA]), cmul(p1A, smaps[s1o + hA]));
    B[j] = cadd(cmul(p0B, smaps[s0o + hB]), cmul(p1B, smaps[s1o + hB]));
  }
  fft320_x2<true>(A, B, ct, tw, lane);
  #pragma unroll
  for (int k = 0; k < 5; ++k) {
    tile[wv*2    ][k + 5*rv6] = A[k];
    tile[wv*2 + 1][k + 5*rv6] = B[k];
  }
  __syncthreads();
  #pragma unroll
  for (int it5 = 0; it5 < 10; ++it5) {
    const int idx = it5 * 256 + tid, u = idx >> 3, d = idx & 7;
    out[((size_t)bc * NN + u) * NN + (r0 + d)] = tile[d][u];   // [bc][kw][h]
  }
}

// Per-iter kernel 2 (R4 exact): FFT_h -> *mask -> IFFT_h -> transposed write.
__global__ __launch_bounds__(256)
void fft_mask_ifft(const c32* __restrict__ in, c32* __restrict__ out,
                   const float* __restrict__ mask, const float* __restrict__ flag,
                   const c32* __restrict__ T320, const c32* __restrict__ T64)
{
  if (flag[0] == 0.f) return;
  __shared__ c32 tile[8][LSTR];
  const int tid = threadIdx.x, lane = tid & 63, wv = tid >> 6;
  const int bc = blockIdx.y, r0 = blockIdx.x * 8;
  LOAD_TWIDDLES
  const int rv6 = __brev((unsigned)lane) >> 26;
  const int rA = r0 + wv*2, rB = rA + 1;
  c32 A[5], B[5];
  #pragma unroll
  for (int j = 0; j < 5; ++j) {
    A[j] = in[((size_t)bc * NN + rA) * NN + lane + 64*j];
    B[j] = in[((size_t)bc * NN + rB) * NN + lane + 64*j];
  }
  fft320_x2<true>(A, B, ct, tw, lane);
  #pragma unroll
  for (int k = 0; k < 5; ++k) {
    const int kh = k + 5*rv6;
    A[k] = cscale(A[k], mask[(size_t)bc * NHW + (size_t)kh * NN + rA]);
    B[k] = cscale(B[k], mask[(size_t)bc * NHW + (size_t)kh * NN + rB]);
  }
  #pragma unroll
  for (int k = 0; k < 5; ++k) {
    tile[wv*2    ][k + 5*rv6] = A[k];
    tile[wv*2 + 1][k + 5*rv6] = B[k];
  }
  #pragma unroll
  for (int j = 0; j < 5; ++j) {
    A[j] = tile[wv*2    ][lane + 64*j];
    B[j] = tile[wv*2 + 1][lane + 64*j];
  }
  fft320_x2<false>(A, B, ct, tw, lane);
  #pragma unroll
  for (int k = 0; k < 5; ++k) {
    tile[wv*2    ][k + 5*rv6] = A[k];
    tile[wv*2 + 1][k + 5*rv6] = B[k];
  }
  __syncthreads();
  #pragma unroll
  for (int it = 0; it < 10; ++it) {
    const int idx = it * 256 + tid, u = idx >> 3, d = idx & 7;
    out[((size_t)bc * NN + u) * NN + (r0 + d)] = tile[d][u];   // [bc][h][kw]
  }
}

// Per-iter kernel 3 (R7 exact): IFFT_w + coil-combine + q = (lam/NHW)*AT + p ; pq partials.
// 4 waves x 3 coils per (b, h-row); LDS tree-reduce; wave 0 emits q + pq.
__global__ __launch_bounds__(256)
void ifft_q(const c32* __restrict__ bufin, const c32* __restrict__ smaps,
            const c32* __restrict__ p, c32* __restrict__ q,
            const float* __restrict__ lam, const float* __restrict__ flag,
            c32* __restrict__ pqpart,
            const c32* __restrict__ T320, const c32* __restrict__ T64)
{
  if (flag[0] == 0.f) return;
  __shared__ c32 tile[QROW][LSTR];
  const int tid = threadIdx.x, lane = tid & 63, wv = tid >> 6;
  const int b = blockIdx.y, h = blockIdx.x;
  LOAD_TWIDDLES
  const int rv6 = __brev((unsigned)lane) >> 26;
  const float lq = lam[0] * (1.f / (float)NHW);
  const size_t rowoff = (size_t)h * NN + lane;
  c32 acc0[5], acc1[5];
  #pragma unroll
  for (int j = 0; j < 5; ++j) { acc0[j] = make_float2(0.f,0.f); acc1[j] = make_float2(0.f,0.f); }

  for (int cc = 0; cc < 3; ++cc) {
    const int c = wv * 3 + cc;
    const size_t ib  = (size_t)(b*NC + c) * NHW + rowoff;
    const size_t is0 = (size_t)((b*NC + c)*NM + 0) * NHW + rowoff;
    const size_t is1 = (size_t)((b*NC + c)*NM + 1) * NHW + rowoff;
    c32 A[5], S0[5], S1[5];
    #pragma unroll
    for (int j = 0; j < 5; ++j) {
      A[j] = bufin[ib + 64*j]; S0[j] = smaps[is0 + 64*j]; S1[j] = smaps[is1 + 64*j];
    }
    fft320_one<false>(A, ct, tw, lane);      // natural kw -> scrambled w
    #pragma unroll
    for (int k = 0; k < 5; ++k) tile[wv][k + 5*rv6] = A[k];   // wave-local unscramble
    #pragma unroll
    for (int j = 0; j < 5; ++j) {
      c32 v = tile[wv][lane + 64*j];
      acc0[j] = cadd(acc0[j], cmulj(S0[j], v));
      acc1[j] = cadd(acc1[j], cmulj(S1[j], v));
    }
  }
  // cross-wave reduce: alias tile as flat scratch (4*LSTR = 1288 c32 >= 1280)
  c32* red = &tile[0][0];
  __syncthreads();
  if (wv >= 2) {
    const int base = (wv - 2) * 640;
    #pragma unroll
    for (int j = 0; j < 5; ++j) {
      red[base + j*64 + lane] = acc0[j];
      red[base + 320 + j*64 + lane] = acc1[j];
    }
  }
  __syncthreads();
  if (wv < 2) {
    const int base = wv * 640;
    #pragma unroll
    for (int j = 0; j < 5; ++j) {
      acc0[j] = cadd(acc0[j], red[base + j*64 + lane]);
      acc1[j] = cadd(acc1[j], red[base + 320 + j*64 + lane]);
    }
  }
  __syncthreads();
  if (wv == 1) {
    #pragma unroll
    for (int j = 0; j < 5; ++j) {
      red[j*64 + lane] = acc0[j];
      red[320 + j*64 + lane] = acc1[j];
    }
  }
  __syncthreads();
  if (wv == 0) {
    const size_t i0 = (size_t)(b*NM + 0) * NHW + rowoff;
    const size_t i1 = (size_t)(b*NM + 1) * NHW + rowoff;
    c32 pqs = make_float2(0.f, 0.f);
    #pragma unroll
    for (int j = 0; j < 5; ++j) {
      acc0[j] = cadd(acc0[j], red[j*64 + lane]);
      acc1[j] = cadd(acc1[j], red[320 + j*64 + lane]);
      c32 p0 = p[i0 + 64*j], p1 = p[i1 + 64*j];
      c32 q0 = cadd(cscale(acc0[j], lq), p0);
      c32 q1 = cadd(cscale(acc1[j], lq), p1);
      q[i0 + 64*j] = q0; q[i1 + 64*j] = q1;
      pqs = cadd(pqs, cadd(cmulj(q0, p0), cmulj(q1, p1)));
    }
    pqs = wave_reduce_c(pqs);
    if (lane == 0) pqpart[b*QBLK + h] = pqs;
  }
}

// Per-iter kernel 4: self-reduce pq -> alpha; x += a p; r -= a q; |r|^2 partials.
__global__ __launch_bounds__(256)
void update1(c32* __restrict__ x, c32* __restrict__ r,
             const c32* __restrict__ p, const c32* __restrict__ q,
             const float* __restrict__ rr, const c32* __restrict__ pqpart,
             const float* __restrict__ flag, float* __restrict__ part,
             const int it)
{
  if (flag[0] == 0.f) return;
  const int b = blockIdx.y;
  const int t = threadIdx.x;
  c32 s = make_float2(0.f, 0.f);
  for (int j = t; j < QBLK; j += 256) s = cadd(s, pqpart[b*QBLK + j]);
  s = wave_reduce_c(s);
  __shared__ c32 spq[4];
  const int lane = t & 63, wv = t >> 6;
  if (lane == 0) spq[wv] = s;
  __syncthreads();
  const c32 pqv = cadd(cadd(spq[0], spq[1]), cadd(spq[2], spq[3]));
  const float rrv = rr[it*NB + b];
  const float den = pqv.x*pqv.x + pqv.y*pqv.y;
  const c32 alpha = make_float2(rrv * pqv.x / den, -rrv * pqv.y / den);
  const int hw = blockIdx.x * 256 + t;
  float acc = 0.f;
  #pragma unroll
  for (int m = 0; m < NM; ++m) {
    const size_t idx = (size_t)(b*NM + m) * NHW + hw;
    c32 pe = p[idx], qe = q[idx];
    c32 xe = cadd(x[idx], cmul(alpha, pe));
    c32 re = csub(r[idx], cmul(alpha, qe));
    x[idx] = xe; r[idx] = re;
    acc += re.x*re.x + re.y*re.y;
  }
  acc = wave_reduce_f(acc);
  __shared__ float sred[4];
  if (lane == 0) sred[wv] = acc;
  __syncthreads();
  if (t == 0) part[b*PBLK + blockIdx.x] = sred[0]+sred[1]+sred[2]+sred[3];
}

extern "C" void kernel_launch(void* const* d_in, const int* in_sizes, int n_in,
                              void* d_out, int out_size, void* d_ws, size_t ws_size,
                              hipStream_t stream)
{
  const c32*  z   = (const c32*)d_in[0];
  const c32*  y   = (const c32*)d_in[1];
  const c32*  sm  = (const c32*)d_in[2];
  const float* mk = (const float*)d_in[3];
  const float* lam= (const float*)d_in[4];
  c32* x = (c32*)d_out;

  char* base = (char*)d_ws;
  size_t off = 0;
  auto walloc = [&](size_t bytes) -> void* {
    void* ptr = base + off;
    off += (bytes + 255) & ~(size_t)255;
    return ptr;
  };
  c32* buf1   = (c32*)walloc((size_t)NBC * NHW * sizeof(c32));
  c32* buf2   = (c32*)walloc((size_t)NBC * NHW * sizeof(c32));
  c32* rv     = (c32*)walloc((size_t)NB * NM * NHW * sizeof(c32));
  c32* pvA    = (c32*)walloc((size_t)NB * NM * NHW * sizeof(c32));
  c32* pvB    = (c32*)walloc((size_t)NB * NM * NHW * sizeof(c32));
  c32* qv     = (c32*)walloc((size_t)NB * NM * NHW * sizeof(c32));
  c32* pqpart = (c32*)walloc((size_t)NB * QBLK * sizeof(c32));
  float* rr   = (float*)walloc((NITER + 1) * NB * sizeof(float));
  float* flags= (float*)walloc((NITER + 1) * sizeof(float));
  float* part1= (float*)walloc((size_t)NB * PBLK * sizeof(float));
  c32* T320   = (c32*)walloc(256 * sizeof(c32));
  c32* T64    = (c32*)walloc(32 * sizeof(c32));
  (void)ws_size; (void)in_sizes; (void)n_in; (void)out_size;

  dim3 blk256(256);
  dim3 fgrid(NN / 8, NBC);           // fft_pass / fft_comb / fft_mask_ifft
  dim3 qgrid(QBLK, NB);              // ifft_q: per (b, h-row)
  dim3 ugrid(PBLK, NB);              // init_combine / update1

  twiddle_init<<<1, blk256, 0, stream>>>(T320, T64);

  // ---- setup: img(buf1) = unnormalized ifft2(y * mask); x0/r/p init + |x0|^2 partials ----
  fft_pass<false, true ><<<fgrid, blk256, 0, stream>>>(y,    buf2, mk,      T320, T64);
  fft_pass<false, false><<<fgrid, blk256, 0, stream>>>(buf2, buf1, nullptr, T320, T64);
  init_combine<<<ugrid, blk256, 0, stream>>>(buf1, sm, z, x, rv, pvA, lam, part1);

  // ---- 10 CG iterations (4 kernels each) ----
  for (int i = 0; i < NITER; ++i) {
    c32* pin  = (i & 1) ? pvA : pvB;        // unused at i==0
    c32* pout = (i & 1) ? pvB : pvA;        // i=0: pvA (holds x0, not rewritten)
    fft_comb<<<fgrid, blk256, 0, stream>>>(buf2, pin, rv, pout, sm, rr, flags, part1, i, T320, T64);
    fft_mask_ifft<<<fgrid, blk256, 0, stream>>>(buf2, buf1, mk, flags + i, T320, T64);
    ifft_q<<<qgrid, blk256, 0, stream>>>(buf1, sm, pout, qv, lam, flags + i, pqpart, T320, T64);
    update1<<<ugrid, blk256, 0, stream>>>(x, rv, pout, qv, rr, pqpart, flags + i, part1, i);
  }
}

// Round 12
// 367.686 us; speedup vs baseline: 2.4164x; 1.0261x over previous
//
#include <hip/hip_runtime.h>
#include <math.h>

#define NB 4
#define NC 12
#define NM 2
#define NN 320
#define NHW (NN*NN)
#define NBC (NB*NC)
#define CG_TOL 1e-6f
#define NITER 10
#define PBLK 400   // |r|^2 partial slots per batch (update1 grid x)
#define QBLK 320   // pq partials per batch (one per h-row)
#define LSTRF 328  // SoA float tile stride: 328 % 32 == 8 -> all accesses <=2-way

#define TWO_PI_F 6.28318530717958647692f

typedef float2 c32;

__device__ __forceinline__ c32 cmul(c32 a, c32 b){ return make_float2(a.x*b.x - a.y*b.y, a.x*b.y + a.y*b.x); }
__device__ __forceinline__ c32 cmulj(c32 a, c32 b){ return make_float2(a.x*b.x + a.y*b.y, a.x*b.y - a.y*b.x); } // conj(a)*b
__device__ __forceinline__ c32 cadd(c32 a, c32 b){ return make_float2(a.x+b.x, a.y+b.y); }
__device__ __forceinline__ c32 csub(c32 a, c32 b){ return make_float2(a.x-b.x, a.y-b.y); }
__device__ __forceinline__ c32 cscale(c32 a, float s){ return make_float2(a.x*s, a.y*s); }

// multiply a by (CONJ ? conj(t) : t) — fwd/inv share one twiddle table
template<bool CONJ>
__device__ __forceinline__ c32 twmul(c32 a, c32 t){
  return CONJ ? make_float2(a.x*t.x + a.y*t.y, a.y*t.x - a.x*t.y)
              : make_float2(a.x*t.x - a.y*t.y, a.y*t.x + a.x*t.y);
}

__device__ __forceinline__ float wave_reduce_f(float v) {
  #pragma unroll
  for (int off = 32; off >= 1; off >>= 1) v += __shfl_xor(v, off, 64);
  return v;
}
__device__ __forceinline__ c32 wave_reduce_c(c32 v) {
  #pragma unroll
  for (int off = 32; off >= 1; off >>= 1) {
    v.x += __shfl_xor(v.x, off, 64);
    v.y += __shfl_xor(v.y, off, 64);
  }
  return v;
}

// T320[j] = cis(2*pi*j/320), j=0..255 ; T64[k] = cis(2*pi*k/64), k=0..31.
__global__ __launch_bounds__(256)
void twiddle_init(c32* __restrict__ T320, c32* __restrict__ T64)
{
  const int t = threadIdx.x;
  {
    float s, c; sincosf(TWO_PI_F * (float)t / 320.f, &s, &c);
    T320[t] = make_float2(c, s);
  }
  if (t < 32) {
    float s, c; sincosf(TWO_PI_F * (float)t / 64.f, &s, &c);
    T64[t] = make_float2(c, s);
  }
}

template<bool FWD>
__device__ __forceinline__ void radix5(c32 V[5]) {
  constexpr float C1 = 0.30901699437494745f;
  constexpr float S1 = 0.9510565162951535f;
  constexpr float C2 = -0.8090169943749475f;
  constexpr float S2 = 0.5877852522924731f;
  constexpr float sg = FWD ? -1.f : 1.f;
  const c32 w1 = make_float2(C1,  sg*S1);
  const c32 w2 = make_float2(C2,  sg*S2);
  const c32 w3 = make_float2(C2, -sg*S2);
  const c32 w4 = make_float2(C1, -sg*S1);
  c32 v0=V[0], v1=V[1], v2=V[2], v3=V[3], v4=V[4];
  V[0] = cadd(cadd(v0, v1), cadd(cadd(v2, v3), v4));
  V[1] = cadd(v0, cadd(cadd(cmul(v1,w1), cmul(v2,w2)), cadd(cmul(v3,w3), cmul(v4,w4))));
  V[2] = cadd(v0, cadd(cadd(cmul(v1,w2), cmul(v2,w4)), cadd(cmul(v3,w1), cmul(v4,w3))));
  V[3] = cadd(v0, cadd(cadd(cmul(v1,w3), cmul(v2,w1)), cadd(cmul(v3,w4), cmul(v4,w2))));
  V[4] = cadd(v0, cadd(cadd(cmul(v1,w4), cmul(v2,w3)), cadd(cmul(v3,w2), cmul(v4,w1))));
}

// Two interleaved 320-pt FFTs (rows A,B): A[j]=x[lane+64j] -> A[k]=X[k+5*rev6(lane)].
template<bool FWD>
__device__ __forceinline__ void fft320_x2(c32 A[5], c32 B[5],
                                          const c32 ct[4], const c32 tw[6], int lane)
{
  radix5<FWD>(A);
  radix5<FWD>(B);
  #pragma unroll
  for (int k = 1; k < 5; ++k) {
    A[k] = twmul<FWD>(A[k], ct[k-1]);
    B[k] = twmul<FWD>(B[k], ct[k-1]);
  }
  #pragma unroll
  for (int s = 0; s < 6; ++s) {
    const int m = 32 >> s;
    const c32 w = tw[s];
    const bool up = (lane & m) != 0;
    c32 oA[5], oB[5];
    #pragma unroll
    for (int k = 0; k < 5; ++k) { oA[k].x = __shfl_xor(A[k].x, m, 64); oA[k].y = __shfl_xor(A[k].y, m, 64); }
    #pragma unroll
    for (int k = 0; k < 5; ++k) { oB[k].x = __shfl_xor(B[k].x, m, 64); oB[k].y = __shfl_xor(B[k].y, m, 64); }
    #pragma unroll
    for (int k = 0; k < 5; ++k) {
      c32 loA = cadd(A[k], oA[k]);
      c32 hiA = twmul<FWD>(csub(oA[k], A[k]), w);
      A[k] = up ? hiA : loA;
      c32 loB = cadd(B[k], oB[k]);
      c32 hiB = twmul<FWD>(csub(oB[k], B[k]), w);
      B[k] = up ? hiB : loB;
    }
  }
}

// One 320-pt FFT per wave (used by ifft_q).
template<bool FWD>
__device__ __forceinline__ void fft320_one(c32 A[5], const c32 ct[4], const c32 tw[6], int lane)
{
  radix5<FWD>(A);
  #pragma unroll
  for (int k = 1; k < 5; ++k) A[k] = twmul<FWD>(A[k], ct[k-1]);
  #pragma unroll
  for (int s = 0; s < 6; ++s) {
    const int m = 32 >> s;
    const c32 w = tw[s];
    const bool up = (lane & m) != 0;
    c32 o[5];
    #pragma unroll
    for (int k = 0; k < 5; ++k) { o[k].x = __shfl_xor(A[k].x, m, 64); o[k].y = __shfl_xor(A[k].y, m, 64); }
    #pragma unroll
    for (int k = 0; k < 5; ++k) {
      c32 lo = cadd(A[k], o[k]);
      c32 hi = twmul<FWD>(csub(o[k], A[k]), w);
      A[k] = up ? hi : lo;
    }
  }
}

#define LOAD_TWIDDLES \
  c32 ct[4], tw[6]; \
  _Pragma("unroll") for (int k_ = 0; k_ < 4; ++k_) ct[k_] = T320[(k_ + 1) * lane]; \
  _Pragma("unroll") for (int s_ = 0; s_ < 6; ++s_) tw[s_] = T64[(lane & ((32 >> s_) - 1)) << s_];

// Batched 1D FFT over contiguous dim of (NBC, NN, NN), transposed write.
// Grid (NBC, NN/8): bc-major -> linear id = bc + 48*ry -> XCD = bc%8 (L2 pinning).
// MASK_IN: multiply input by mask.
template<bool FWD, bool MASK_IN>
__global__ __launch_bounds__(256)
void fft_pass(const c32* __restrict__ in, c32* __restrict__ out,
              const float* __restrict__ mask,
              const c32* __restrict__ T320, const c32* __restrict__ T64)
{
  __shared__ float tX[8][LSTRF], tY[8][LSTRF];
  const int tid = threadIdx.x, lane = tid & 63, wv = tid >> 6;
  const int bc = blockIdx.x, r0 = blockIdx.y * 8;
  LOAD_TWIDDLES
  const int rv6 = __brev((unsigned)lane) >> 26;
  const int rA = r0 + wv*2, rB = rA + 1;
  c32 A[5], B[5];
  #pragma unroll
  for (int j = 0; j < 5; ++j) {
    const size_t iA = ((size_t)bc * NN + rA) * NN + lane + 64*j;
    const size_t iB = ((size_t)bc * NN + rB) * NN + lane + 64*j;
    A[j] = in[iA]; B[j] = in[iB];
    if constexpr (MASK_IN) { A[j] = cscale(A[j], mask[iA]); B[j] = cscale(B[j], mask[iB]); }
  }
  fft320_x2<FWD>(A, B, ct, tw, lane);
  #pragma unroll
  for (int k = 0; k < 5; ++k) {
    const int i = k + 5*rv6;
    tX[wv*2    ][i] = A[k].x; tY[wv*2    ][i] = A[k].y;
    tX[wv*2 + 1][i] = B[k].x; tY[wv*2 + 1][i] = B[k].y;
  }
  __syncthreads();
  #pragma unroll
  for (int it = 0; it < 10; ++it) {
    const int idx = it * 256 + tid, u = idx >> 3, d = idx & 7;
    out[((size_t)bc * NN + u) * NN + (r0 + d)] = make_float2(tX[d][u], tY[d][u]);
  }
}

// x0 = (lam/NN)*sum_c conj(sm)*img + z ; x=0, r=p=x0 ; |x0|^2 partials
__global__ __launch_bounds__(256)
void init_combine(const c32* __restrict__ img, const c32* __restrict__ smaps,
                  const c32* __restrict__ z, c32* __restrict__ x,
                  c32* __restrict__ r, c32* __restrict__ p,
                  const float* __restrict__ lam, float* __restrict__ part)
{
  const int b  = blockIdx.y;
  const int hw = blockIdx.x * 256 + threadIdx.x;
  const float l0 = lam[0] * (1.f / (float)NN);
  c32 a0 = make_float2(0.f,0.f), a1 = make_float2(0.f,0.f);
  #pragma unroll
  for (int c = 0; c < NC; ++c) {
    c32 iv = img[(size_t)(b*NC + c) * NHW + hw];
    c32 s0 = smaps[(size_t)((b*NC + c)*NM + 0) * NHW + hw];
    c32 s1 = smaps[(size_t)((b*NC + c)*NM + 1) * NHW + hw];
    a0 = cadd(a0, cmulj(s0, iv));
    a1 = cadd(a1, cmulj(s1, iv));
  }
  const size_t i0 = (size_t)(b*NM + 0) * NHW + hw;
  const size_t i1 = (size_t)(b*NM + 1) * NHW + hw;
  c32 x00 = cadd(cscale(a0, l0), z[i0]);
  c32 x01 = cadd(cscale(a1, l0), z[i1]);
  x[i0] = make_float2(0.f,0.f); x[i1] = make_float2(0.f,0.f);
  r[i0] = x00; r[i1] = x01;
  p[i0] = x00; p[i1] = x01;
  float acc = x00.x*x00.x + x00.y*x00.y + x01.x*x01.x + x01.y*x01.y;
  acc = wave_reduce_f(acc);
  __shared__ float sred[4];
  const int lane = threadIdx.x & 63, wv = threadIdx.x >> 6;
  if (lane == 0) sred[wv] = acc;
  __syncthreads();
  if (threadIdx.x == 0) part[b*PBLK + blockIdx.x] = sred[0]+sred[1]+sred[2]+sred[3];
}

// Per-iter kernel 1: self-reduce part1 -> rr_it, flag, beta; publish rr[it]/flags[it];
// p_new = r + beta*p_prev; coil-combine; FFT_w; transposed write. Grid (NBC, NN/8).
__global__ __launch_bounds__(256)
void fft_comb(c32* __restrict__ out, const c32* __restrict__ pin,
              const c32* __restrict__ rres, c32* __restrict__ pout,
              const c32* __restrict__ smaps,
              float* __restrict__ rr, float* __restrict__ flags,
              const float* __restrict__ part1, const int it,
              const c32* __restrict__ T320, const c32* __restrict__ T64)
{
  __shared__ float tX[8][LSTRF], tY[8][LSTRF];
  __shared__ float sstat[NB];
  const int tid = threadIdx.x, lane = tid & 63, wv = tid >> 6;
  const int bc = blockIdx.x, r0 = blockIdx.y * 8;
  const int b = bc / NC, c = bc - b * NC;
  // repeat-dead fast exit: once flags go 0 they stay 0
  if (it > 0 && flags[it-1] == 0.f) {
    if (blockIdx.x == 0 && blockIdx.y == 0 && tid == 0) flags[it] = 0.f;
    return;
  }
  // head: waves 0..3 reduce batch wv's partials (L2-hot, 1.6 KB each)
  {
    float s = 0.f;
    for (int j = lane; j < PBLK; j += 64) s += part1[wv*PBLK + j];
    s = wave_reduce_f(s);
    if (lane == 0) sstat[wv] = s;
  }
  __syncthreads();
  float flag;
  if (it == 0) flag = 1.f;
  else {
    float mn = 1e30f;
    #pragma unroll
    for (int bb = 0; bb < NB; ++bb) mn = fminf(mn, sstat[bb] / rr[bb]);  // rr[0..3] = rr_0 = x0x0
    flag = (mn > CG_TOL) ? 1.f : 0.f;
  }
  if (tid < NB) rr[it*NB + tid] = sstat[tid];   // identical redundant writes
  if (tid == 0) flags[it] = flag;
  if (it != 0 && flag == 0.f) return;
  const float beta = (it != 0) ? sstat[b] / rr[(it-1)*NB + b] : 0.f;
  const bool upd = (it != 0);

  LOAD_TWIDDLES
  const int rv6 = __brev((unsigned)lane) >> 26;
  const int rA = r0 + wv*2, rB = rA + 1;
  const size_t m0 = (size_t)(b*NM + 0) * NHW, m1 = (size_t)(b*NM + 1) * NHW;
  const size_t s0o = (size_t)((b*NC + c)*NM + 0) * NHW, s1o = (size_t)((b*NC + c)*NM + 1) * NHW;
  c32 A[5], B[5];
  #pragma unroll
  for (int j = 0; j < 5; ++j) {
    const size_t hA = (size_t)rA * NN + lane + 64*j;
    const size_t hB = (size_t)rB * NN + lane + 64*j;
    c32 r0A = rres[m0 + hA], r1A = rres[m1 + hA];
    c32 r0B = rres[m0 + hB], r1B = rres[m1 + hB];
    c32 p0A, p1A, p0B, p1B;
    if (upd) {
      p0A = cadd(r0A, cscale(pin[m0 + hA], beta));
      p1A = cadd(r1A, cscale(pin[m1 + hA], beta));
      p0B = cadd(r0B, cscale(pin[m0 + hB], beta));
      p1B = cadd(r1B, cscale(pin[m1 + hB], beta));
      if (c == 0) {
        pout[m0 + hA] = p0A; pout[m1 + hA] = p1A;
        pout[m0 + hB] = p0B; pout[m1 + hB] = p1B;
      }
    } else {
      p0A = r0A; p1A = r1A; p0B = r0B; p1B = r1B;   // iter 0: p = r = x0
    }
    A[j] = cadd(cmul(p0A, smaps[s0o + hA]), cmul(p1A, smaps[s1o + hA]));
    B[j] = cadd(cmul(p0B, smaps[s0o + hB]), cmul(p1B, smaps[s1o + hB]));
  }
  fft320_x2<true>(A, B, ct, tw, lane);
  #pragma unroll
  for (int k = 0; k < 5; ++k) {
    const int i = k + 5*rv6;
    tX[wv*2    ][i] = A[k].x; tY[wv*2    ][i] = A[k].y;
    tX[wv*2 + 1][i] = B[k].x; tY[wv*2 + 1][i] = B[k].y;
  }
  __syncthreads();
  #pragma unroll
  for (int it5 = 0; it5 < 10; ++it5) {
    const int idx = it5 * 256 + tid, u = idx >> 3, d = idx & 7;
    out[((size_t)bc * NN + u) * NN + (r0 + d)] = make_float2(tX[d][u], tY[d][u]);   // [bc][kw][h]
  }
}

// Per-iter kernel 2: FFT_h -> *mask -> IFFT_h -> transposed write. Grid (NBC, NN/8).
__global__ __launch_bounds__(256)
void fft_mask_ifft(const c32* __restrict__ in, c32* __restrict__ out,
                   const float* __restrict__ mask, const float* __restrict__ flag,
                   const c32* __restrict__ T320, const c32* __restrict__ T64)
{
  if (flag[0] == 0.f) return;
  __shared__ float tX[8][LSTRF], tY[8][LSTRF];
  const int tid = threadIdx.x, lane = tid & 63, wv = tid >> 6;
  const int bc = blockIdx.x, r0 = blockIdx.y * 8;
  LOAD_TWIDDLES
  const int rv6 = __brev((unsigned)lane) >> 26;
  const int rA = r0 + wv*2, rB = rA + 1;
  c32 A[5], B[5];
  #pragma unroll
  for (int j = 0; j < 5; ++j) {
    A[j] = in[((size_t)bc * NN + rA) * NN + lane + 64*j];
    B[j] = in[((size_t)bc * NN + rB) * NN + lane + 64*j];
  }
  fft320_x2<true>(A, B, ct, tw, lane);
  #pragma unroll
  for (int k = 0; k < 5; ++k) {
    const int kh = k + 5*rv6;
    A[k] = cscale(A[k], mask[(size_t)bc * NHW + (size_t)kh * NN + rA]);
    B[k] = cscale(B[k], mask[(size_t)bc * NHW + (size_t)kh * NN + rB]);
  }
  // unscramble through wave-owned LDS rows (in-wave DS ordering; no barrier)
  #pragma unroll
  for (int k = 0; k < 5; ++k) {
    const int i = k + 5*rv6;
    tX[wv*2    ][i] = A[k].x; tY[wv*2    ][i] = A[k].y;
    tX[wv*2 + 1][i] = B[k].x; tY[wv*2 + 1][i] = B[k].y;
  }
  #pragma unroll
  for (int j = 0; j < 5; ++j) {
    const int i = lane + 64*j;
    A[j] = make_float2(tX[wv*2][i], tY[wv*2][i]);
    B[j] = make_float2(tX[wv*2 + 1][i], tY[wv*2 + 1][i]);
  }
  fft320_x2<false>(A, B, ct, tw, lane);
  #pragma unroll
  for (int k = 0; k < 5; ++k) {
    const int i = k + 5*rv6;
    tX[wv*2    ][i] = A[k].x; tY[wv*2    ][i] = A[k].y;
    tX[wv*2 + 1][i] = B[k].x; tY[wv*2 + 1][i] = B[k].y;
  }
  __syncthreads();
  #pragma unroll
  for (int it = 0; it < 10; ++it) {
    const int idx = it * 256 + tid, u = idx >> 3, d = idx & 7;
    out[((size_t)bc * NN + u) * NN + (r0 + d)] = make_float2(tX[d][u], tY[d][u]);   // [bc][h][kw]
  }
}

// Per-iter kernel 3: IFFT_w + coil-combine + q = (lam/NHW)*AT + p ; pq partials.
// 4 waves x 3 coils per (b, h-row); LDS tree-reduce; wave 0 emits q + pq.
__global__ __launch_bounds__(256)
void ifft_q(const c32* __restrict__ bufin, const c32* __restrict__ smaps,
            const c32* __restrict__ p, c32* __restrict__ q,
            const float* __restrict__ lam, const float* __restrict__ flag,
            c32* __restrict__ pqpart,
            const c32* __restrict__ T320, const c32* __restrict__ T64)
{
  if (flag[0] == 0.f) return;
  __shared__ float tX[4][LSTRF], tY[4][LSTRF];
  const int tid = threadIdx.x, lane = tid & 63, wv = tid >> 6;
  const int b = blockIdx.y, h = blockIdx.x;
  LOAD_TWIDDLES
  const int rv6 = __brev((unsigned)lane) >> 26;
  const float lq = lam[0] * (1.f / (float)NHW);
  const size_t rowoff = (size_t)h * NN + lane;
  c32 acc0[5], acc1[5];
  #pragma unroll
  for (int j = 0; j < 5; ++j) { acc0[j] = make_float2(0.f,0.f); acc1[j] = make_float2(0.f,0.f); }

  for (int cc = 0; cc < 3; ++cc) {
    const int c = wv * 3 + cc;
    const size_t ib  = (size_t)(b*NC + c) * NHW + rowoff;
    const size_t is0 = (size_t)((b*NC + c)*NM + 0) * NHW + rowoff;
    const size_t is1 = (size_t)((b*NC + c)*NM + 1) * NHW + rowoff;
    c32 A[5], S0[5], S1[5];
    #pragma unroll
    for (int j = 0; j < 5; ++j) {
      A[j] = bufin[ib + 64*j]; S0[j] = smaps[is0 + 64*j]; S1[j] = smaps[is1 + 64*j];
    }
    fft320_one<false>(A, ct, tw, lane);      // natural kw -> scrambled w
    // wave-local unscramble (in-wave DS ordering; no block sync)
    #pragma unroll
    for (int k = 0; k < 5; ++k) {
      const int i = k + 5*rv6;
      tX[wv][i] = A[k].x; tY[wv][i] = A[k].y;
    }
    #pragma unroll
    for (int j = 0; j < 5; ++j) {
      const int i = lane + 64*j;
      c32 v = make_float2(tX[wv][i], tY[wv][i]);
      acc0[j] = cadd(acc0[j], cmulj(S0[j], v));
      acc1[j] = cadd(acc1[j], cmulj(S1[j], v));
    }
  }
  // cross-wave reduce: alias tiles as flat scratch (4*LSTRF = 1312 floats >= 1280)
  float* redX = &tX[0][0];
  float* redY = &tY[0][0];
  __syncthreads();
  if (wv >= 2) {
    const int base = (wv - 2) * 640;
    #pragma unroll
    for (int j = 0; j < 5; ++j) {
      redX[base + j*64 + lane] = acc0[j].x; redY[base + j*64 + lane] = acc0[j].y;
      redX[base + 320 + j*64 + lane] = acc1[j].x; redY[base + 320 + j*64 + lane] = acc1[j].y;
    }
  }
  __syncthreads();
  if (wv < 2) {
    const int base = wv * 640;
    #pragma unroll
    for (int j = 0; j < 5; ++j) {
      acc0[j] = cadd(acc0[j], make_float2(redX[base + j*64 + lane], redY[base + j*64 + lane]));
      acc1[j] = cadd(acc1[j], make_float2(redX[base + 320 + j*64 + lane], redY[base + 320 + j*64 + lane]));
    }
  }
  __syncthreads();
  if (wv == 1) {
    #pragma unroll
    for (int j = 0; j < 5; ++j) {
      redX[j*64 + lane] = acc0[j].x; redY[j*64 + lane] = acc0[j].y;
      redX[320 + j*64 + lane] = acc1[j].x; redY[320 + j*64 + lane] = acc1[j].y;
    }
  }
  __syncthreads();
  if (wv == 0) {
    const size_t i0 = (size_t)(b*NM + 0) * NHW + rowoff;
    const size_t i1 = (size_t)(b*NM + 1) * NHW + rowoff;
    c32 pqs = make_float2(0.f, 0.f);
    #pragma unroll
    for (int j = 0; j < 5; ++j) {
      acc0[j] = cadd(acc0[j], make_float2(redX[j*64 + lane], redY[j*64 + lane]));
      acc1[j] = cadd(acc1[j], make_float2(redX[320 + j*64 + lane], redY[320 + j*64 + lane]));
      c32 p0 = p[i0 + 64*j], p1 = p[i1 + 64*j];
      c32 q0 = cadd(cscale(acc0[j], lq), p0);
      c32 q1 = cadd(cscale(acc1[j], lq), p1);
      q[i0 + 64*j] = q0; q[i1 + 64*j] = q1;
      pqs = cadd(pqs, cadd(cmulj(q0, p0), cmulj(q1, p1)));
    }
    pqs = wave_reduce_c(pqs);
    if (lane == 0) pqpart[b*QBLK + h] = pqs;
  }
}

// Per-iter kernel 4: self-reduce pq -> alpha; x += a p; r -= a q; |r|^2 partials.
__global__ __launch_bounds__(256)
void update1(c32* __restrict__ x, c32* __restrict__ r,
             const c32* __restrict__ p, const c32* __restrict__ q,
             const float* __restrict__ rr, const c32* __restrict__ pqpart,
             const float* __restrict__ flag, float* __restrict__ part,
             const int it)
{
  if (flag[0] == 0.f) return;
  const int b = blockIdx.y;
  const int t = threadIdx.x;
  c32 s = make_float2(0.f, 0.f);
  for (int j = t; j < QBLK; j += 256) s = cadd(s, pqpart[b*QBLK + j]);
  s = wave_reduce_c(s);
  __shared__ c32 spq[4];
  const int lane = t & 63, wv = t >> 6;
  if (lane == 0) spq[wv] = s;
  __syncthreads();
  const c32 pqv = cadd(cadd(spq[0], spq[1]), cadd(spq[2], spq[3]));
  const float rrv = rr[it*NB + b];
  const float den = pqv.x*pqv.x + pqv.y*pqv.y;
  const c32 alpha = make_float2(rrv * pqv.x / den, -rrv * pqv.y / den);
  const int hw = blockIdx.x * 256 + t;
  float acc = 0.f;
  #pragma unroll
  for (int m = 0; m < NM; ++m) {
    const size_t idx = (size_t)(b*NM + m) * NHW + hw;
    c32 pe = p[idx], qe = q[idx];
    c32 xe = cadd(x[idx], cmul(alpha, pe));
    c32 re = csub(r[idx], cmul(alpha, qe));
    x[idx] = xe; r[idx] = re;
    acc += re.x*re.x + re.y*re.y;
  }
  acc = wave_reduce_f(acc);
  __shared__ float sred[4];
  if (lane == 0) sred[wv] = acc;
  __syncthreads();
  if (t == 0) part[b*PBLK + blockIdx.x] = sred[0]+sred[1]+sred[2]+sred[3];
}

extern "C" void kernel_launch(void* const* d_in, const int* in_sizes, int n_in,
                              void* d_out, int out_size, void* d_ws, size_t ws_size,
                              hipStream_t stream)
{
  const c32*  z   = (const c32*)d_in[0];
  const c32*  y   = (const c32*)d_in[1];
  const c32*  sm  = (const c32*)d_in[2];
  const float* mk = (const float*)d_in[3];
  const float* lam= (const float*)d_in[4];
  c32* x = (c32*)d_out;

  char* base = (char*)d_ws;
  size_t off = 0;
  auto walloc = [&](size_t bytes) -> void* {
    void* ptr = base + off;
    off += (bytes + 255) & ~(size_t)255;
    return ptr;
  };
  c32* buf1   = (c32*)walloc((size_t)NBC * NHW * sizeof(c32));
  c32* buf2   = (c32*)walloc((size_t)NBC * NHW * sizeof(c32));
  c32* rv     = (c32*)walloc((size_t)NB * NM * NHW * sizeof(c32));
  c32* pvA    = (c32*)walloc((size_t)NB * NM * NHW * sizeof(c32));
  c32* pvB    = (c32*)walloc((size_t)NB * NM * NHW * sizeof(c32));
  c32* qv     = (c32*)walloc((size_t)NB * NM * NHW * sizeof(c32));
  c32* pqpart = (c32*)walloc((size_t)NB * QBLK * sizeof(c32));
  float* rr   = (float*)walloc((NITER + 1) * NB * sizeof(float));
  float* flags= (float*)walloc((NITER + 1) * sizeof(float));
  float* part1= (float*)walloc((size_t)NB * PBLK * sizeof(float));
  c32* T320   = (c32*)walloc(256 * sizeof(c32));
  c32* T64    = (c32*)walloc(32 * sizeof(c32));
  (void)ws_size; (void)in_sizes; (void)n_in; (void)out_size;

  dim3 blk256(256);
  dim3 fgrid(NBC, NN / 8);           // bc-major: XCD = bc % 8 (L2 producer/consumer pinning)
  dim3 qgrid(QBLK, NB);              // ifft_q: per (b, h-row)
  dim3 ugrid(PBLK, NB);              // init_combine / update1

  twiddle_init<<<1, blk256, 0, stream>>>(T320, T64);

  // ---- setup: img(buf1) = unnormalized ifft2(y * mask); x0/r/p init + |x0|^2 partials ----
  fft_pass<false, true ><<<fgrid, blk256, 0, stream>>>(y,    buf2, mk,      T320, T64);
  fft_pass<false, false><<<fgrid, blk256, 0, stream>>>(buf2, buf1, nullptr, T320, T64);
  init_combine<<<ugrid, blk256, 0, stream>>>(buf1, sm, z, x, rv, pvA, lam, part1);

  // ---- 10 CG iterations (4 kernels each) ----
  for (int i = 0; i < NITER; ++i) {
    c32* pin  = (i & 1) ? pvA : pvB;        // unused at i==0
    c32* pout = (i & 1) ? pvB : pvA;        // i=0: pvA (holds x0, not rewritten)
    fft_comb<<<fgrid, blk256, 0, stream>>>(buf2, pin, rv, pout, sm, rr, flags, part1, i, T320, T64);
    fft_mask_ifft<<<fgrid, blk256, 0, stream>>>(buf2, buf1, mk, flags + i, T320, T64);
    ifft_q<<<qgrid, blk256, 0, stream>>>(buf1, sm, pout, qv, lam, flags + i, pqpart, T320, T64);
    update1<<<ugrid, blk256, 0, stream>>>(x, rv, pout, qv, rr, pqpart, flags + i, part1, i);
  }
}

// Round 13
// 366.376 us; speedup vs baseline: 2.4250x; 1.0036x over previous
//
#include <hip/hip_runtime.h>
#include <math.h>

#define NB 4
#define NC 12
#define NM 2
#define NN 320
#define NHW (NN*NN)
#define NBC (NB*NC)
#define CG_TOL 1e-6f
#define NITER 10
#define PBLK 400   // |r|^2 partial slots per batch (update1 grid x)
#define QBLK 320   // pq partials per batch (one per h-row)
#define LSTRF 324  // SoA float tile stride: 324 % 32 == 4 -> <=2-way conflicts;
                   // 2*8*324*4 = 20736 B keeps 3 blocks/CU (21504 dropped to 2 - R12 regression)

#define TWO_PI_F 6.28318530717958647692f

typedef float2 c32;

__device__ __forceinline__ c32 cmul(c32 a, c32 b){ return make_float2(a.x*b.x - a.y*b.y, a.x*b.y + a.y*b.x); }
__device__ __forceinline__ c32 cmulj(c32 a, c32 b){ return make_float2(a.x*b.x + a.y*b.y, a.x*b.y - a.y*b.x); } // conj(a)*b
__device__ __forceinline__ c32 cadd(c32 a, c32 b){ return make_float2(a.x+b.x, a.y+b.y); }
__device__ __forceinline__ c32 csub(c32 a, c32 b){ return make_float2(a.x-b.x, a.y-b.y); }
__device__ __forceinline__ c32 cscale(c32 a, float s){ return make_float2(a.x*s, a.y*s); }

// multiply a by (CONJ ? conj(t) : t) — fwd/inv share one twiddle table
template<bool CONJ>
__device__ __forceinline__ c32 twmul(c32 a, c32 t){
  return CONJ ? make_float2(a.x*t.x + a.y*t.y, a.y*t.x - a.x*t.y)
              : make_float2(a.x*t.x - a.y*t.y, a.y*t.x + a.x*t.y);
}

__device__ __forceinline__ float wave_reduce_f(float v) {
  #pragma unroll
  for (int off = 32; off >= 1; off >>= 1) v += __shfl_xor(v, off, 64);
  return v;
}
__device__ __forceinline__ c32 wave_reduce_c(c32 v) {
  #pragma unroll
  for (int off = 32; off >= 1; off >>= 1) {
    v.x += __shfl_xor(v.x, off, 64);
    v.y += __shfl_xor(v.y, off, 64);
  }
  return v;
}

// T320[j] = cis(2*pi*j/320), j=0..255 ; T64[k] = cis(2*pi*k/64), k=0..31.
__global__ __launch_bounds__(256)
void twiddle_init(c32* __restrict__ T320, c32* __restrict__ T64)
{
  const int t = threadIdx.x;
  {
    float s, c; sincosf(TWO_PI_F * (float)t / 320.f, &s, &c);
    T320[t] = make_float2(c, s);
  }
  if (t < 32) {
    float s, c; sincosf(TWO_PI_F * (float)t / 64.f, &s, &c);
    T64[t] = make_float2(c, s);
  }
}

template<bool FWD>
__device__ __forceinline__ void radix5(c32 V[5]) {
  constexpr float C1 = 0.30901699437494745f;
  constexpr float S1 = 0.9510565162951535f;
  constexpr float C2 = -0.8090169943749475f;
  constexpr float S2 = 0.5877852522924731f;
  constexpr float sg = FWD ? -1.f : 1.f;
  const c32 w1 = make_float2(C1,  sg*S1);
  const c32 w2 = make_float2(C2,  sg*S2);
  const c32 w3 = make_float2(C2, -sg*S2);
  const c32 w4 = make_float2(C1, -sg*S1);
  c32 v0=V[0], v1=V[1], v2=V[2], v3=V[3], v4=V[4];
  V[0] = cadd(cadd(v0, v1), cadd(cadd(v2, v3), v4));
  V[1] = cadd(v0, cadd(cadd(cmul(v1,w1), cmul(v2,w2)), cadd(cmul(v3,w3), cmul(v4,w4))));
  V[2] = cadd(v0, cadd(cadd(cmul(v1,w2), cmul(v2,w4)), cadd(cmul(v3,w1), cmul(v4,w3))));
  V[3] = cadd(v0, cadd(cadd(cmul(v1,w3), cmul(v2,w1)), cadd(cmul(v3,w4), cmul(v4,w2))));
  V[4] = cadd(v0, cadd(cadd(cmul(v1,w4), cmul(v2,w3)), cadd(cmul(v3,w2), cmul(v4,w1))));
}

// Two interleaved 320-pt FFTs (rows A,B): A[j]=x[lane+64j] -> A[k]=X[k+5*rev6(lane)].
template<bool FWD>
__device__ __forceinline__ void fft320_x2(c32 A[5], c32 B[5],
                                          const c32 ct[4], const c32 tw[6], int lane)
{
  radix5<FWD>(A);
  radix5<FWD>(B);
  #pragma unroll
  for (int k = 1; k < 5; ++k) {
    A[k] = twmul<FWD>(A[k], ct[k-1]);
    B[k] = twmul<FWD>(B[k], ct[k-1]);
  }
  #pragma unroll
  for (int s = 0; s < 6; ++s) {
    const int m = 32 >> s;
    const c32 w = tw[s];
    const bool up = (lane & m) != 0;
    c32 oA[5], oB[5];
    #pragma unroll
    for (int k = 0; k < 5; ++k) { oA[k].x = __shfl_xor(A[k].x, m, 64); oA[k].y = __shfl_xor(A[k].y, m, 64); }
    #pragma unroll
    for (int k = 0; k < 5; ++k) { oB[k].x = __shfl_xor(B[k].x, m, 64); oB[k].y = __shfl_xor(B[k].y, m, 64); }
    #pragma unroll
    for (int k = 0; k < 5; ++k) {
      c32 loA = cadd(A[k], oA[k]);
      c32 hiA = twmul<FWD>(csub(oA[k], A[k]), w);
      A[k] = up ? hiA : loA;
      c32 loB = cadd(B[k], oB[k]);
      c32 hiB = twmul<FWD>(csub(oB[k], B[k]), w);
      B[k] = up ? hiB : loB;
    }
  }
}

// One 320-pt FFT per wave (used by ifft_q).
template<bool FWD>
__device__ __forceinline__ void fft320_one(c32 A[5], const c32 ct[4], const c32 tw[6], int lane)
{
  radix5<FWD>(A);
  #pragma unroll
  for (int k = 1; k < 5; ++k) A[k] = twmul<FWD>(A[k], ct[k-1]);
  #pragma unroll
  for (int s = 0; s < 6; ++s) {
    const int m = 32 >> s;
    const c32 w = tw[s];
    const bool up = (lane & m) != 0;
    c32 o[5];
    #pragma unroll
    for (int k = 0; k < 5; ++k) { o[k].x = __shfl_xor(A[k].x, m, 64); o[k].y = __shfl_xor(A[k].y, m, 64); }
    #pragma unroll
    for (int k = 0; k < 5; ++k) {
      c32 lo = cadd(A[k], o[k]);
      c32 hi = twmul<FWD>(csub(o[k], A[k]), w);
      A[k] = up ? hi : lo;
    }
  }
}

#define LOAD_TWIDDLES \
  c32 ct[4], tw[6]; \
  _Pragma("unroll") for (int k_ = 0; k_ < 4; ++k_) ct[k_] = T320[(k_ + 1) * lane]; \
  _Pragma("unroll") for (int s_ = 0; s_ < 6; ++s_) tw[s_] = T64[(lane & ((32 >> s_) - 1)) << s_];

// Batched 1D FFT over contiguous dim of (NBC, NN, NN), transposed write.
// Grid (NBC, NN/8): bc-major -> linear id = bc + 48*ry -> XCD = bc%8 (L2 pinning).
// MASK_IN: multiply input by mask.
template<bool FWD, bool MASK_IN>
__global__ __launch_bounds__(256)
void fft_pass(const c32* __restrict__ in, c32* __restrict__ out,
              const float* __restrict__ mask,
              const c32* __restrict__ T320, const c32* __restrict__ T64)
{
  __shared__ float tX[8][LSTRF], tY[8][LSTRF];
  const int tid = threadIdx.x, lane = tid & 63, wv = tid >> 6;
  const int bc = blockIdx.x, r0 = blockIdx.y * 8;
  LOAD_TWIDDLES
  const int rv6 = __brev((unsigned)lane) >> 26;
  const int rA = r0 + wv*2, rB = rA + 1;
  c32 A[5], B[5];
  #pragma unroll
  for (int j = 0; j < 5; ++j) {
    const size_t iA = ((size_t)bc * NN + rA) * NN + lane + 64*j;
    const size_t iB = ((size_t)bc * NN + rB) * NN + lane + 64*j;
    A[j] = in[iA]; B[j] = in[iB];
    if constexpr (MASK_IN) { A[j] = cscale(A[j], mask[iA]); B[j] = cscale(B[j], mask[iB]); }
  }
  fft320_x2<FWD>(A, B, ct, tw, lane);
  #pragma unroll
  for (int k = 0; k < 5; ++k) {
    const int i = k + 5*rv6;
    tX[wv*2    ][i] = A[k].x; tY[wv*2    ][i] = A[k].y;
    tX[wv*2 + 1][i] = B[k].x; tY[wv*2 + 1][i] = B[k].y;
  }
  __syncthreads();
  #pragma unroll
  for (int it = 0; it < 10; ++it) {
    const int idx = it * 256 + tid, u = idx >> 3, d = idx & 7;
    out[((size_t)bc * NN + u) * NN + (r0 + d)] = make_float2(tX[d][u], tY[d][u]);
  }
}

// x0 = (lam/NN)*sum_c conj(sm)*img + z ; x=0, r=p=x0 ; |x0|^2 partials
__global__ __launch_bounds__(256)
void init_combine(const c32* __restrict__ img, const c32* __restrict__ smaps,
                  const c32* __restrict__ z, c32* __restrict__ x,
                  c32* __restrict__ r, c32* __restrict__ p,
                  const float* __restrict__ lam, float* __restrict__ part)
{
  const int b  = blockIdx.y;
  const int hw = blockIdx.x * 256 + threadIdx.x;
  const float l0 = lam[0] * (1.f / (float)NN);
  c32 a0 = make_float2(0.f,0.f), a1 = make_float2(0.f,0.f);
  #pragma unroll
  for (int c = 0; c < NC; ++c) {
    c32 iv = img[(size_t)(b*NC + c) * NHW + hw];
    c32 s0 = smaps[(size_t)((b*NC + c)*NM + 0) * NHW + hw];
    c32 s1 = smaps[(size_t)((b*NC + c)*NM + 1) * NHW + hw];
    a0 = cadd(a0, cmulj(s0, iv));
    a1 = cadd(a1, cmulj(s1, iv));
  }
  const size_t i0 = (size_t)(b*NM + 0) * NHW + hw;
  const size_t i1 = (size_t)(b*NM + 1) * NHW + hw;
  c32 x00 = cadd(cscale(a0, l0), z[i0]);
  c32 x01 = cadd(cscale(a1, l0), z[i1]);
  x[i0] = make_float2(0.f,0.f); x[i1] = make_float2(0.f,0.f);
  r[i0] = x00; r[i1] = x01;
  p[i0] = x00; p[i1] = x01;
  float acc = x00.x*x00.x + x00.y*x00.y + x01.x*x01.x + x01.y*x01.y;
  acc = wave_reduce_f(acc);
  __shared__ float sred[4];
  const int lane = threadIdx.x & 63, wv = threadIdx.x >> 6;
  if (lane == 0) sred[wv] = acc;
  __syncthreads();
  if (threadIdx.x == 0) part[b*PBLK + blockIdx.x] = sred[0]+sred[1]+sred[2]+sred[3];
}

// Per-iter kernel 1: self-reduce part1 -> rr_it, flag, beta; publish rr[it]/flags[it];
// p_new = r + beta*p_prev; coil-combine; FFT_w; transposed write. Grid (NBC, NN/8).
__global__ __launch_bounds__(256)
void fft_comb(c32* __restrict__ out, const c32* __restrict__ pin,
              const c32* __restrict__ rres, c32* __restrict__ pout,
              const c32* __restrict__ smaps,
              float* __restrict__ rr, float* __restrict__ flags,
              const float* __restrict__ part1, const int it,
              const c32* __restrict__ T320, const c32* __restrict__ T64)
{
  __shared__ float tX[8][LSTRF], tY[8][LSTRF];
  __shared__ float sstat[NB];
  const int tid = threadIdx.x, lane = tid & 63, wv = tid >> 6;
  const int bc = blockIdx.x, r0 = blockIdx.y * 8;
  const int b = bc / NC, c = bc - b * NC;
  // repeat-dead fast exit: once flags go 0 they stay 0
  if (it > 0 && flags[it-1] == 0.f) {
    if (blockIdx.x == 0 && blockIdx.y == 0 && tid == 0) flags[it] = 0.f;
    return;
  }
  // head: waves 0..3 reduce batch wv's partials (L2-hot, 1.6 KB each)
  {
    float s = 0.f;
    for (int j = lane; j < PBLK; j += 64) s += part1[wv*PBLK + j];
    s = wave_reduce_f(s);
    if (lane == 0) sstat[wv] = s;
  }
  __syncthreads();
  float flag;
  if (it == 0) flag = 1.f;
  else {
    float mn = 1e30f;
    #pragma unroll
    for (int bb = 0; bb < NB; ++bb) mn = fminf(mn, sstat[bb] / rr[bb]);  // rr[0..3] = rr_0 = x0x0
    flag = (mn > CG_TOL) ? 1.f : 0.f;
  }
  if (tid < NB) rr[it*NB + tid] = sstat[tid];   // identical redundant writes
  if (tid == 0) flags[it] = flag;
  if (it != 0 && flag == 0.f) return;
  const float beta = (it != 0) ? sstat[b] / rr[(it-1)*NB + b] : 0.f;
  const bool upd = (it != 0);

  LOAD_TWIDDLES
  const int rv6 = __brev((unsigned)lane) >> 26;
  const int rA = r0 + wv*2, rB = rA + 1;
  const size_t m0 = (size_t)(b*NM + 0) * NHW, m1 = (size_t)(b*NM + 1) * NHW;
  const size_t s0o = (size_t)((b*NC + c)*NM + 0) * NHW, s1o = (size_t)((b*NC + c)*NM + 1) * NHW;
  c32 A[5], B[5];
  #pragma unroll
  for (int j = 0; j < 5; ++j) {
    const size_t hA = (size_t)rA * NN + lane + 64*j;
    const size_t hB = (size_t)rB * NN + lane + 64*j;
    c32 r0A = rres[m0 + hA], r1A = rres[m1 + hA];
    c32 r0B = rres[m0 + hB], r1B = rres[m1 + hB];
    c32 p0A, p1A, p0B, p1B;
    if (upd) {
      p0A = cadd(r0A, cscale(pin[m0 + hA], beta));
      p1A = cadd(r1A, cscale(pin[m1 + hA], beta));
      p0B = cadd(r0B, cscale(pin[m0 + hB], beta));
      p1B = cadd(r1B, cscale(pin[m1 + hB], beta));
      if (c == 0) {
        pout[m0 + hA] = p0A; pout[m1 + hA] = p1A;
        pout[m0 + hB] = p0B; pout[m1 + hB] = p1B;
      }
    } else {
      p0A = r0A; p1A = r1A; p0B = r0B; p1B = r1B;   // iter 0: p = r = x0
    }
    A[j] = cadd(cmul(p0A, smaps[s0o + hA]), cmul(p1A, smaps[s1o + hA]));
    B[j] = cadd(cmul(p0B, smaps[s0o + hB]), cmul(p1B, smaps[s1o + hB]));
  }
  fft320_x2<true>(A, B, ct, tw, lane);
  #pragma unroll
  for (int k = 0; k < 5; ++k) {
    const int i = k + 5*rv6;
    tX[wv*2    ][i] = A[k].x; tY[wv*2    ][i] = A[k].y;
    tX[wv*2 + 1][i] = B[k].x; tY[wv*2 + 1][i] = B[k].y;
  }
  __syncthreads();
  #pragma unroll
  for (int it5 = 0; it5 < 10; ++it5) {
    const int idx = it5 * 256 + tid, u = idx >> 3, d = idx & 7;
    out[((size_t)bc * NN + u) * NN + (r0 + d)] = make_float2(tX[d][u], tY[d][u]);   // [bc][kw][h]
  }
}

// Per-iter kernel 2: FFT_h -> *mask -> IFFT_h -> transposed write. Grid (NBC, NN/8).
__global__ __launch_bounds__(256)
void fft_mask_ifft(const c32* __restrict__ in, c32* __restrict__ out,
                   const float* __restrict__ mask, const float* __restrict__ flag,
                   const c32* __restrict__ T320, const c32* __restrict__ T64)
{
  if (flag[0] == 0.f) return;
  __shared__ float tX[8][LSTRF], tY[8][LSTRF];
  const int tid = threadIdx.x, lane = tid & 63, wv = tid >> 6;
  const int bc = blockIdx.x, r0 = blockIdx.y * 8;
  LOAD_TWIDDLES
  const int rv6 = __brev((unsigned)lane) >> 26;
  const int rA = r0 + wv*2, rB = rA + 1;
  c32 A[5], B[5];
  #pragma unroll
  for (int j = 0; j < 5; ++j) {
    A[j] = in[((size_t)bc * NN + rA) * NN + lane + 64*j];
    B[j] = in[((size_t)bc * NN + rB) * NN + lane + 64*j];
  }
  fft320_x2<true>(A, B, ct, tw, lane);
  #pragma unroll
  for (int k = 0; k < 5; ++k) {
    const int kh = k + 5*rv6;
    A[k] = cscale(A[k], mask[(size_t)bc * NHW + (size_t)kh * NN + rA]);
    B[k] = cscale(B[k], mask[(size_t)bc * NHW + (size_t)kh * NN + rB]);
  }
  // unscramble through wave-owned LDS rows (in-wave DS ordering; no barrier)
  #pragma unroll
  for (int k = 0; k < 5; ++k) {
    const int i = k + 5*rv6;
    tX[wv*2    ][i] = A[k].x; tY[wv*2    ][i] = A[k].y;
    tX[wv*2 + 1][i] = B[k].x; tY[wv*2 + 1][i] = B[k].y;
  }
  #pragma unroll
  for (int j = 0; j < 5; ++j) {
    const int i = lane + 64*j;
    A[j] = make_float2(tX[wv*2][i], tY[wv*2][i]);
    B[j] = make_float2(tX[wv*2 + 1][i], tY[wv*2 + 1][i]);
  }
  fft320_x2<false>(A, B, ct, tw, lane);
  #pragma unroll
  for (int k = 0; k < 5; ++k) {
    const int i = k + 5*rv6;
    tX[wv*2    ][i] = A[k].x; tY[wv*2    ][i] = A[k].y;
    tX[wv*2 + 1][i] = B[k].x; tY[wv*2 + 1][i] = B[k].y;
  }
  __syncthreads();
  #pragma unroll
  for (int it = 0; it < 10; ++it) {
    const int idx = it * 256 + tid, u = idx >> 3, d = idx & 7;
    out[((size_t)bc * NN + u) * NN + (r0 + d)] = make_float2(tX[d][u], tY[d][u]);   // [bc][h][kw]
  }
}

// Per-iter kernel 3: IFFT_w + coil-combine + q = (lam/NHW)*AT + p ; pq partials.
// 4 waves x 3 coils per (b, h-row); LDS tree-reduce; wave 0 emits q + pq.
__global__ __launch_bounds__(256)
void ifft_q(const c32* __restrict__ bufin, const c32* __restrict__ smaps,
            const c32* __restrict__ p, c32* __restrict__ q,
            const float* __restrict__ lam, const float* __restrict__ flag,
            c32* __restrict__ pqpart,
            const c32* __restrict__ T320, const c32* __restrict__ T64)
{
  if (flag[0] == 0.f) return;
  __shared__ float tX[4][LSTRF], tY[4][LSTRF];
  const int tid = threadIdx.x, lane = tid & 63, wv = tid >> 6;
  const int b = blockIdx.y, h = blockIdx.x;
  LOAD_TWIDDLES
  const int rv6 = __brev((unsigned)lane) >> 26;
  const float lq = lam[0] * (1.f / (float)NHW);
  const size_t rowoff = (size_t)h * NN + lane;
  c32 acc0[5], acc1[5];
  #pragma unroll
  for (int j = 0; j < 5; ++j) { acc0[j] = make_float2(0.f,0.f); acc1[j] = make_float2(0.f,0.f); }

  for (int cc = 0; cc < 3; ++cc) {
    const int c = wv * 3 + cc;
    const size_t ib  = (size_t)(b*NC + c) * NHW + rowoff;
    const size_t is0 = (size_t)((b*NC + c)*NM + 0) * NHW + rowoff;
    const size_t is1 = (size_t)((b*NC + c)*NM + 1) * NHW + rowoff;
    c32 A[5], S0[5], S1[5];
    #pragma unroll
    for (int j = 0; j < 5; ++j) {
      A[j] = bufin[ib + 64*j]; S0[j] = smaps[is0 + 64*j]; S1[j] = smaps[is1 + 64*j];
    }
    fft320_one<false>(A, ct, tw, lane);      // natural kw -> scrambled w
    // wave-local unscramble (in-wave DS ordering; no block sync)
    #pragma unroll
    for (int k = 0; k < 5; ++k) {
      const int i = k + 5*rv6;
      tX[wv][i] = A[k].x; tY[wv][i] = A[k].y;
    }
    #pragma unroll
    for (int j = 0; j < 5; ++j) {
      const int i = lane + 64*j;
      c32 v = make_float2(tX[wv][i], tY[wv][i]);
      acc0[j] = cadd(acc0[j], cmulj(S0[j], v));
      acc1[j] = cadd(acc1[j], cmulj(S1[j], v));
    }
  }
  // cross-wave reduce: alias tiles as flat scratch (4*LSTRF = 1296 floats >= 1280)
  float* redX = &tX[0][0];
  float* redY = &tY[0][0];
  __syncthreads();
  if (wv >= 2) {
    const int base = (wv - 2) * 640;
    #pragma unroll
    for (int j = 0; j < 5; ++j) {
      redX[base + j*64 + lane] = acc0[j].x; redY[base + j*64 + lane] = acc0[j].y;
      redX[base + 320 + j*64 + lane] = acc1[j].x; redY[base + 320 + j*64 + lane] = acc1[j].y;
    }
  }
  __syncthreads();
  if (wv < 2) {
    const int base = wv * 640;
    #pragma unroll
    for (int j = 0; j < 5; ++j) {
      acc0[j] = cadd(acc0[j], make_float2(redX[base + j*64 + lane], redY[base + j*64 + lane]));
      acc1[j] = cadd(acc1[j], make_float2(redX[base + 320 + j*64 + lane], redY[base + 320 + j*64 + lane]));
    }
  }
  __syncthreads();
  if (wv == 1) {
    #pragma unroll
    for (int j = 0; j < 5; ++j) {
      redX[j*64 + lane] = acc0[j].x; redY[j*64 + lane] = acc0[j].y;
      redX[320 + j*64 + lane] = acc1[j].x; redY[320 + j*64 + lane] = acc1[j].y;
    }
  }
  __syncthreads();
  if (wv == 0) {
    const size_t i0 = (size_t)(b*NM + 0) * NHW + rowoff;
    const size_t i1 = (size_t)(b*NM + 1) * NHW + rowoff;
    c32 pqs = make_float2(0.f, 0.f);
    #pragma unroll
    for (int j = 0; j < 5; ++j) {
      acc0[j] = cadd(acc0[j], make_float2(redX[j*64 + lane], redY[j*64 + lane]));
      acc1[j] = cadd(acc1[j], make_float2(redX[320 + j*64 + lane], redY[320 + j*64 + lane]));
      c32 p0 = p[i0 + 64*j], p1 = p[i1 + 64*j];
      c32 q0 = cadd(cscale(acc0[j], lq), p0);
      c32 q1 = cadd(cscale(acc1[j], lq), p1);
      q[i0 + 64*j] = q0; q[i1 + 64*j] = q1;
      pqs = cadd(pqs, cadd(cmulj(q0, p0), cmulj(q1, p1)));
    }
    pqs = wave_reduce_c(pqs);
    if (lane == 0) pqpart[b*QBLK + h] = pqs;
  }
}

// Per-iter kernel 4: self-reduce pq -> alpha; x += a p; r -= a q; |r|^2 partials.
__global__ __launch_bounds__(256)
void update1(c32* __restrict__ x, c32* __restrict__ r,
             const c32* __restrict__ p, const c32* __restrict__ q,
             const float* __restrict__ rr, const c32* __restrict__ pqpart,
             const float* __restrict__ flag, float* __restrict__ part,
             const int it)
{
  if (flag[0] == 0.f) return;
  const int b = blockIdx.y;
  const int t = threadIdx.x;
  c32 s = make_float2(0.f, 0.f);
  for (int j = t; j < QBLK; j += 256) s = cadd(s, pqpart[b*QBLK + j]);
  s = wave_reduce_c(s);
  __shared__ c32 spq[4];
  const int lane = t & 63, wv = t >> 6;
  if (lane == 0) spq[wv] = s;
  __syncthreads();
  const c32 pqv = cadd(cadd(spq[0], spq[1]), cadd(spq[2], spq[3]));
  const float rrv = rr[it*NB + b];
  const float den = pqv.x*pqv.x + pqv.y*pqv.y;
  const c32 alpha = make_float2(rrv * pqv.x / den, -rrv * pqv.y / den);
  const int hw = blockIdx.x * 256 + t;
  float acc = 0.f;
  #pragma unroll
  for (int m = 0; m < NM; ++m) {
    const size_t idx = (size_t)(b*NM + m) * NHW + hw;
    c32 pe = p[idx], qe = q[idx];
    c32 xe = cadd(x[idx], cmul(alpha, pe));
    c32 re = csub(r[idx], cmul(alpha, qe));
    x[idx] = xe; r[idx] = re;
    acc += re.x*re.x + re.y*re.y;
  }
  acc = wave_reduce_f(acc);
  __shared__ float sred[4];
  if (lane == 0) sred[wv] = acc;
  __syncthreads();
  if (t == 0) part[b*PBLK + blockIdx.x] = sred[0]+sred[1]+sred[2]+sred[3];
}

extern "C" void kernel_launch(void* const* d_in, const int* in_sizes, int n_in,
                              void* d_out, int out_size, void* d_ws, size_t ws_size,
                              hipStream_t stream)
{
  const c32*  z   = (const c32*)d_in[0];
  const c32*  y   = (const c32*)d_in[1];
  const c32*  sm  = (const c32*)d_in[2];
  const float* mk = (const float*)d_in[3];
  const float* lam= (const float*)d_in[4];
  c32* x = (c32*)d_out;

  char* base = (char*)d_ws;
  size_t off = 0;
  auto walloc = [&](size_t bytes) -> void* {
    void* ptr = base + off;
    off += (bytes + 255) & ~(size_t)255;
    return ptr;
  };
  c32* buf1   = (c32*)walloc((size_t)NBC * NHW * sizeof(c32));
  c32* buf2   = (c32*)walloc((size_t)NBC * NHW * sizeof(c32));
  c32* rv     = (c32*)walloc((size_t)NB * NM * NHW * sizeof(c32));
  c32* pvA    = (c32*)walloc((size_t)NB * NM * NHW * sizeof(c32));
  c32* pvB    = (c32*)walloc((size_t)NB * NM * NHW * sizeof(c32));
  c32* qv     = (c32*)walloc((size_t)NB * NM * NHW * sizeof(c32));
  c32* pqpart = (c32*)walloc((size_t)NB * QBLK * sizeof(c32));
  float* rr   = (float*)walloc((NITER + 1) * NB * sizeof(float));
  float* flags= (float*)walloc((NITER + 1) * sizeof(float));
  float* part1= (float*)walloc((size_t)NB * PBLK * sizeof(float));
  c32* T320   = (c32*)walloc(256 * sizeof(c32));
  c32* T64    = (c32*)walloc(32 * sizeof(c32));
  (void)ws_size; (void)in_sizes; (void)n_in; (void)out_size;

  dim3 blk256(256);
  dim3 fgrid(NBC, NN / 8);           // bc-major: XCD = bc % 8 (L2 producer/consumer pinning)
  dim3 qgrid(QBLK, NB);              // ifft_q: per (b, h-row)
  dim3 ugrid(PBLK, NB);              // init_combine / update1

  twiddle_init<<<1, blk256, 0, stream>>>(T320, T64);

  // ---- setup: img(buf1) = unnormalized ifft2(y * mask); x0/r/p init + |x0|^2 partials ----
  fft_pass<false, true ><<<fgrid, blk256, 0, stream>>>(y,    buf2, mk,      T320, T64);
  fft_pass<false, false><<<fgrid, blk256, 0, stream>>>(buf2, buf1, nullptr, T320, T64);
  init_combine<<<ugrid, blk256, 0, stream>>>(buf1, sm, z, x, rv, pvA, lam, part1);

  // ---- 10 CG iterations (4 kernels each) ----
  for (int i = 0; i < NITER; ++i) {
    c32* pin  = (i & 1) ? pvA : pvB;        // unused at i==0
    c32* pout = (i & 1) ? pvB : pvA;        // i=0: pvA (holds x0, not rewritten)
    fft_comb<<<fgrid, blk256, 0, stream>>>(buf2, pin, rv, pout, sm, rr, flags, part1, i, T320, T64);
    fft_mask_ifft<<<fgrid, blk256, 0, stream>>>(buf2, buf1, mk, flags + i, T320, T64);
    ifft_q<<<qgrid, blk256, 0, stream>>>(buf1, sm, pout, qv, lam, flags + i, pqpart, T320, T64);
    update1<<<ugrid, blk256, 0, stream>>>(x, rv, pout, qv, rr, pqpart, flags + i, part1, i);
  }
}

// Round 14
// 364.092 us; speedup vs baseline: 2.4402x; 1.0063x over previous
//
#include <hip/hip_runtime.h>
#include <math.h>

#define NB 4
#define NC 12
#define NM 2
#define NN 320
#define NHW (NN*NN)
#define NBC (NB*NC)
#define CG_TOL 1e-6f
#define NITER 10
#define PBLK 400   // |r|^2 partial slots per batch (update1 grid x)
#define QBLK 320   // pq partials per batch (one per h-row)
#define LSTRF 324  // SoA float tile stride: 324 % 32 == 4 -> <=2-way conflicts; 20736 B/block

#define TWO_PI_F 6.28318530717958647692f

typedef float2 c32;

__device__ __forceinline__ c32 cmul(c32 a, c32 b){ return make_float2(a.x*b.x - a.y*b.y, a.x*b.y + a.y*b.x); }
__device__ __forceinline__ c32 cmulj(c32 a, c32 b){ return make_float2(a.x*b.x + a.y*b.y, a.x*b.y - a.y*b.x); } // conj(a)*b
__device__ __forceinline__ c32 cadd(c32 a, c32 b){ return make_float2(a.x+b.x, a.y+b.y); }
__device__ __forceinline__ c32 csub(c32 a, c32 b){ return make_float2(a.x-b.x, a.y-b.y); }
__device__ __forceinline__ c32 cscale(c32 a, float s){ return make_float2(a.x*s, a.y*s); }

// multiply a by (CONJ ? conj(t) : t) — fwd/inv share one twiddle table
template<bool CONJ>
__device__ __forceinline__ c32 twmul(c32 a, c32 t){
  return CONJ ? make_float2(a.x*t.x + a.y*t.y, a.y*t.x - a.x*t.y)
              : make_float2(a.x*t.x - a.y*t.y, a.y*t.x + a.x*t.y);
}

__device__ __forceinline__ float wave_reduce_f(float v) {
  #pragma unroll
  for (int off = 32; off >= 1; off >>= 1) v += __shfl_xor(v, off, 64);
  return v;
}
__device__ __forceinline__ c32 wave_reduce_c(c32 v) {
  #pragma unroll
  for (int off = 32; off >= 1; off >>= 1) {
    v.x += __shfl_xor(v.x, off, 64);
    v.y += __shfl_xor(v.y, off, 64);
  }
  return v;
}

// T320[j] = cis(2*pi*j/320), j=0..255 ; T64[k] = cis(2*pi*k/64), k=0..31.
__global__ __launch_bounds__(256)
void twiddle_init(c32* __restrict__ T320, c32* __restrict__ T64)
{
  const int t = threadIdx.x;
  {
    float s, c; sincosf(TWO_PI_F * (float)t / 320.f, &s, &c);
    T320[t] = make_float2(c, s);
  }
  if (t < 32) {
    float s, c; sincosf(TWO_PI_F * (float)t / 64.f, &s, &c);
    T64[t] = make_float2(c, s);
  }
}

template<bool FWD>
__device__ __forceinline__ void radix5(c32 V[5]) {
  constexpr float C1 = 0.30901699437494745f;
  constexpr float S1 = 0.9510565162951535f;
  constexpr float C2 = -0.8090169943749475f;
  constexpr float S2 = 0.5877852522924731f;
  constexpr float sg = FWD ? -1.f : 1.f;
  const c32 w1 = make_float2(C1,  sg*S1);
  const c32 w2 = make_float2(C2,  sg*S2);
  const c32 w3 = make_float2(C2, -sg*S2);
  const c32 w4 = make_float2(C1, -sg*S1);
  c32 v0=V[0], v1=V[1], v2=V[2], v3=V[3], v4=V[4];
  V[0] = cadd(cadd(v0, v1), cadd(cadd(v2, v3), v4));
  V[1] = cadd(v0, cadd(cadd(cmul(v1,w1), cmul(v2,w2)), cadd(cmul(v3,w3), cmul(v4,w4))));
  V[2] = cadd(v0, cadd(cadd(cmul(v1,w2), cmul(v2,w4)), cadd(cmul(v3,w1), cmul(v4,w3))));
  V[3] = cadd(v0, cadd(cadd(cmul(v1,w3), cmul(v2,w1)), cadd(cmul(v3,w4), cmul(v4,w2))));
  V[4] = cadd(v0, cadd(cadd(cmul(v1,w4), cmul(v2,w3)), cadd(cmul(v3,w2), cmul(v4,w1))));
}

// One 320-pt FFT per wave: A[j]=x[lane+64j] (natural) -> A[k]=X[k+5*rev6(lane)] (scrambled).
template<bool FWD>
__device__ __forceinline__ void fft320_one(c32 A[5], const c32 ct[4], const c32 tw[6], int lane)
{
  radix5<FWD>(A);
  #pragma unroll
  for (int k = 1; k < 5; ++k) A[k] = twmul<FWD>(A[k], ct[k-1]);
  #pragma unroll
  for (int s = 0; s < 6; ++s) {
    const int m = 32 >> s;
    const c32 w = tw[s];
    const bool up = (lane & m) != 0;
    c32 o[5];
    #pragma unroll
    for (int k = 0; k < 5; ++k) { o[k].x = __shfl_xor(A[k].x, m, 64); o[k].y = __shfl_xor(A[k].y, m, 64); }
    #pragma unroll
    for (int k = 0; k < 5; ++k) {
      c32 lo = cadd(A[k], o[k]);
      c32 hi = twmul<FWD>(csub(o[k], A[k]), w);
      A[k] = up ? hi : lo;
    }
  }
}

#define LOAD_TWIDDLES \
  c32 ct[4], tw[6]; \
  _Pragma("unroll") for (int k_ = 0; k_ < 4; ++k_) ct[k_] = T320[(k_ + 1) * lane]; \
  _Pragma("unroll") for (int s_ = 0; s_ < 6; ++s_) tw[s_] = T64[(lane & ((32 >> s_) - 1)) << s_];

// Batched 1D FFT over contiguous dim of (NBC, NN, NN), transposed write.
// 512 threads, 8 waves, 1 row/wave. Grid (NBC, NN/8): XCD = bc%8 (L2 pinning).
template<bool FWD, bool MASK_IN>
__global__ __launch_bounds__(512)
void fft_pass(const c32* __restrict__ in, c32* __restrict__ out,
              const float* __restrict__ mask,
              const c32* __restrict__ T320, const c32* __restrict__ T64)
{
  __shared__ float tX[8][LSTRF], tY[8][LSTRF];
  const int tid = threadIdx.x, lane = tid & 63, wv = tid >> 6;
  const int bc = blockIdx.x, r0 = blockIdx.y * 8;
  LOAD_TWIDDLES
  const int rv6 = __brev((unsigned)lane) >> 26;
  const int row = r0 + wv;
  c32 A[5];
  #pragma unroll
  for (int j = 0; j < 5; ++j) {
    const size_t idx = ((size_t)bc * NN + row) * NN + lane + 64*j;
    A[j] = in[idx];
    if constexpr (MASK_IN) A[j] = cscale(A[j], mask[idx]);
  }
  fft320_one<FWD>(A, ct, tw, lane);
  #pragma unroll
  for (int k = 0; k < 5; ++k) {
    const int i = k + 5*rv6;
    tX[wv][i] = A[k].x; tY[wv][i] = A[k].y;
  }
  __syncthreads();
  #pragma unroll
  for (int it = 0; it < 5; ++it) {
    const int idx = it * 512 + tid, u = idx >> 3, d = idx & 7;
    out[((size_t)bc * NN + u) * NN + (r0 + d)] = make_float2(tX[d][u], tY[d][u]);
  }
}

// x0 = (lam/NN)*sum_c conj(sm)*img + z ; x=0, r=p=x0 ; |x0|^2 partials
__global__ __launch_bounds__(256)
void init_combine(const c32* __restrict__ img, const c32* __restrict__ smaps,
                  const c32* __restrict__ z, c32* __restrict__ x,
                  c32* __restrict__ r, c32* __restrict__ p,
                  const float* __restrict__ lam, float* __restrict__ part)
{
  const int b  = blockIdx.y;
  const int hw = blockIdx.x * 256 + threadIdx.x;
  const float l0 = lam[0] * (1.f / (float)NN);
  c32 a0 = make_float2(0.f,0.f), a1 = make_float2(0.f,0.f);
  #pragma unroll
  for (int c = 0; c < NC; ++c) {
    c32 iv = img[(size_t)(b*NC + c) * NHW + hw];
    c32 s0 = smaps[(size_t)((b*NC + c)*NM + 0) * NHW + hw];
    c32 s1 = smaps[(size_t)((b*NC + c)*NM + 1) * NHW + hw];
    a0 = cadd(a0, cmulj(s0, iv));
    a1 = cadd(a1, cmulj(s1, iv));
  }
  const size_t i0 = (size_t)(b*NM + 0) * NHW + hw;
  const size_t i1 = (size_t)(b*NM + 1) * NHW + hw;
  c32 x00 = cadd(cscale(a0, l0), z[i0]);
  c32 x01 = cadd(cscale(a1, l0), z[i1]);
  x[i0] = make_float2(0.f,0.f); x[i1] = make_float2(0.f,0.f);
  r[i0] = x00; r[i1] = x01;
  p[i0] = x00; p[i1] = x01;
  float acc = x00.x*x00.x + x00.y*x00.y + x01.x*x01.x + x01.y*x01.y;
  acc = wave_reduce_f(acc);
  __shared__ float sred[4];
  const int lane = threadIdx.x & 63, wv = threadIdx.x >> 6;
  if (lane == 0) sred[wv] = acc;
  __syncthreads();
  if (threadIdx.x == 0) part[b*PBLK + blockIdx.x] = sred[0]+sred[1]+sred[2]+sred[3];
}

// Per-iter kernel 1: self-reduce part1 -> rr_it, flag, beta; publish rr[it]/flags[it];
// p_new = r + beta*p_prev; coil-combine; FFT_w; transposed write. 512 thr, 1 row/wave.
__global__ __launch_bounds__(512)
void fft_comb(c32* __restrict__ out, const c32* __restrict__ pin,
              const c32* __restrict__ rres, c32* __restrict__ pout,
              const c32* __restrict__ smaps,
              float* __restrict__ rr, float* __restrict__ flags,
              const float* __restrict__ part1, const int it,
              const c32* __restrict__ T320, const c32* __restrict__ T64)
{
  __shared__ float tX[8][LSTRF], tY[8][LSTRF];
  __shared__ float sstat[NB];
  const int tid = threadIdx.x, lane = tid & 63, wv = tid >> 6;
  const int bc = blockIdx.x, r0 = blockIdx.y * 8;
  const int b = bc / NC, c = bc - b * NC;
  // repeat-dead fast exit: once flags go 0 they stay 0
  if (it > 0 && flags[it-1] == 0.f) {
    if (blockIdx.x == 0 && blockIdx.y == 0 && tid == 0) flags[it] = 0.f;
    return;
  }
  // head: waves 0..3 reduce batch wv's partials (L2-hot, 1.6 KB each)
  if (wv < NB) {
    float s = 0.f;
    for (int j = lane; j < PBLK; j += 64) s += part1[wv*PBLK + j];
    s = wave_reduce_f(s);
    if (lane == 0) sstat[wv] = s;
  }
  __syncthreads();
  float flag;
  if (it == 0) flag = 1.f;
  else {
    float mn = 1e30f;
    #pragma unroll
    for (int bb = 0; bb < NB; ++bb) mn = fminf(mn, sstat[bb] / rr[bb]);  // rr[0..3] = rr_0 = x0x0
    flag = (mn > CG_TOL) ? 1.f : 0.f;
  }
  if (tid < NB) rr[it*NB + tid] = sstat[tid];   // identical redundant writes
  if (tid == 0) flags[it] = flag;
  if (it != 0 && flag == 0.f) return;
  const float beta = (it != 0) ? sstat[b] / rr[(it-1)*NB + b] : 0.f;
  const bool upd = (it != 0);

  LOAD_TWIDDLES
  const int rv6 = __brev((unsigned)lane) >> 26;
  const int row = r0 + wv;
  const size_t m0 = (size_t)(b*NM + 0) * NHW, m1 = (size_t)(b*NM + 1) * NHW;
  const size_t s0o = (size_t)((b*NC + c)*NM + 0) * NHW, s1o = (size_t)((b*NC + c)*NM + 1) * NHW;
  c32 A[5];
  #pragma unroll
  for (int j = 0; j < 5; ++j) {
    const size_t h = (size_t)row * NN + lane + 64*j;
    c32 r0v = rres[m0 + h], r1v = rres[m1 + h];
    c32 p0, p1;
    if (upd) {
      p0 = cadd(r0v, cscale(pin[m0 + h], beta));
      p1 = cadd(r1v, cscale(pin[m1 + h], beta));
      if (c == 0) { pout[m0 + h] = p0; pout[m1 + h] = p1; }
    } else { p0 = r0v; p1 = r1v; }   // iter 0: p = r = x0
    A[j] = cadd(cmul(p0, smaps[s0o + h]), cmul(p1, smaps[s1o + h]));
  }
  fft320_one<true>(A, ct, tw, lane);
  #pragma unroll
  for (int k = 0; k < 5; ++k) {
    const int i = k + 5*rv6;
    tX[wv][i] = A[k].x; tY[wv][i] = A[k].y;
  }
  __syncthreads();
  #pragma unroll
  for (int it5 = 0; it5 < 5; ++it5) {
    const int idx = it5 * 512 + tid, u = idx >> 3, d = idx & 7;
    out[((size_t)bc * NN + u) * NN + (r0 + d)] = make_float2(tX[d][u], tY[d][u]);   // [bc][kw][h]
  }
}

// Per-iter kernel 2: FFT_h -> *mask -> IFFT_h -> transposed write. 512 thr, 1 row/wave.
__global__ __launch_bounds__(512)
void fft_mask_ifft(const c32* __restrict__ in, c32* __restrict__ out,
                   const float* __restrict__ mask, const float* __restrict__ flag,
                   const c32* __restrict__ T320, const c32* __restrict__ T64)
{
  if (flag[0] == 0.f) return;
  __shared__ float tX[8][LSTRF], tY[8][LSTRF];
  const int tid = threadIdx.x, lane = tid & 63, wv = tid >> 6;
  const int bc = blockIdx.x, r0 = blockIdx.y * 8;
  LOAD_TWIDDLES
  const int rv6 = __brev((unsigned)lane) >> 26;
  const int row = r0 + wv;   // k_w index
  c32 A[5];
  #pragma unroll
  for (int j = 0; j < 5; ++j)
    A[j] = in[((size_t)bc * NN + row) * NN + lane + 64*j];
  fft320_one<true>(A, ct, tw, lane);
  // mask in scrambled order: k_h = k + 5*rev6(lane)
  #pragma unroll
  for (int k = 0; k < 5; ++k) {
    const int kh = k + 5*rv6;
    A[k] = cscale(A[k], mask[(size_t)bc * NHW + (size_t)kh * NN + row]);
  }
  // unscramble through wave-owned LDS row (in-wave DS ordering; no barrier)
  #pragma unroll
  for (int k = 0; k < 5; ++k) {
    const int i = k + 5*rv6;
    tX[wv][i] = A[k].x; tY[wv][i] = A[k].y;
  }
  #pragma unroll
  for (int j = 0; j < 5; ++j) {
    const int i = lane + 64*j;
    A[j] = make_float2(tX[wv][i], tY[wv][i]);
  }
  fft320_one<false>(A, ct, tw, lane);
  #pragma unroll
  for (int k = 0; k < 5; ++k) {
    const int i = k + 5*rv6;
    tX[wv][i] = A[k].x; tY[wv][i] = A[k].y;
  }
  __syncthreads();
  #pragma unroll
  for (int it = 0; it < 5; ++it) {
    const int idx = it * 512 + tid, u = idx >> 3, d = idx & 7;
    out[((size_t)bc * NN + u) * NN + (r0 + d)] = make_float2(tX[d][u], tY[d][u]);   // [bc][h][kw]
  }
}

// Per-iter kernel 3: IFFT_w + coil-combine + q = (lam/NHW)*AT + p ; pq partials.
// 4 waves x 3 coils per (b, h-row); LDS tree-reduce; wave 0 emits q + pq.
__global__ __launch_bounds__(256)
void ifft_q(const c32* __restrict__ bufin, const c32* __restrict__ smaps,
            const c32* __restrict__ p, c32* __restrict__ q,
            const float* __restrict__ lam, const float* __restrict__ flag,
            c32* __restrict__ pqpart,
            const c32* __restrict__ T320, const c32* __restrict__ T64)
{
  if (flag[0] == 0.f) return;
  __shared__ float tX[4][LSTRF], tY[4][LSTRF];
  const int tid = threadIdx.x, lane = tid & 63, wv = tid >> 6;
  const int b = blockIdx.y, h = blockIdx.x;
  LOAD_TWIDDLES
  const int rv6 = __brev((unsigned)lane) >> 26;
  const float lq = lam[0] * (1.f / (float)NHW);
  const size_t rowoff = (size_t)h * NN + lane;
  c32 acc0[5], acc1[5];
  #pragma unroll
  for (int j = 0; j < 5; ++j) { acc0[j] = make_float2(0.f,0.f); acc1[j] = make_float2(0.f,0.f); }

  for (int cc = 0; cc < 3; ++cc) {
    const int c = wv * 3 + cc;
    const size_t ib  = (size_t)(b*NC + c) * NHW + rowoff;
    const size_t is0 = (size_t)((b*NC + c)*NM + 0) * NHW + rowoff;
    const size_t is1 = (size_t)((b*NC + c)*NM + 1) * NHW + rowoff;
    c32 A[5], S0[5], S1[5];
    #pragma unroll
    for (int j = 0; j < 5; ++j) {
      A[j] = bufin[ib + 64*j]; S0[j] = smaps[is0 + 64*j]; S1[j] = smaps[is1 + 64*j];
    }
    fft320_one<false>(A, ct, tw, lane);      // natural kw -> scrambled w
    // wave-local unscramble (in-wave DS ordering; no block sync)
    #pragma unroll
    for (int k = 0; k < 5; ++k) {
      const int i = k + 5*rv6;
      tX[wv][i] = A[k].x; tY[wv][i] = A[k].y;
    }
    #pragma unroll
    for (int j = 0; j < 5; ++j) {
      const int i = lane + 64*j;
      c32 v = make_float2(tX[wv][i], tY[wv][i]);
      acc0[j] = cadd(acc0[j], cmulj(S0[j], v));
      acc1[j] = cadd(acc1[j], cmulj(S1[j], v));
    }
  }
  // cross-wave reduce: alias tiles as flat scratch (4*LSTRF = 1296 floats >= 1280)
  float* redX = &tX[0][0];
  float* redY = &tY[0][0];
  __syncthreads();
  if (wv >= 2) {
    const int base = (wv - 2) * 640;
    #pragma unroll
    for (int j = 0; j < 5; ++j) {
      redX[base + j*64 + lane] = acc0[j].x; redY[base + j*64 + lane] = acc0[j].y;
      redX[base + 320 + j*64 + lane] = acc1[j].x; redY[base + 320 + j*64 + lane] = acc1[j].y;
    }
  }
  __syncthreads();
  if (wv < 2) {
    const int base = wv * 640;
    #pragma unroll
    for (int j = 0; j < 5; ++j) {
      acc0[j] = cadd(acc0[j], make_float2(redX[base + j*64 + lane], redY[base + j*64 + lane]));
      acc1[j] = cadd(acc1[j], make_float2(redX[base + 320 + j*64 + lane], redY[base + 320 + j*64 + lane]));
    }
  }
  __syncthreads();
  if (wv == 1) {
    #pragma unroll
    for (int j = 0; j < 5; ++j) {
      redX[j*64 + lane] = acc0[j].x; redY[j*64 + lane] = acc0[j].y;
      redX[320 + j*64 + lane] = acc1[j].x; redY[320 + j*64 + lane] = acc1[j].y;
    }
  }
  __syncthreads();
  if (wv == 0) {
    const size_t i0 = (size_t)(b*NM + 0) * NHW + rowoff;
    const size_t i1 = (size_t)(b*NM + 1) * NHW + rowoff;
    c32 pqs = make_float2(0.f, 0.f);
    #pragma unroll
    for (int j = 0; j < 5; ++j) {
      acc0[j] = cadd(acc0[j], make_float2(redX[j*64 + lane], redY[j*64 + lane]));
      acc1[j] = cadd(acc1[j], make_float2(redX[320 + j*64 + lane], redY[320 + j*64 + lane]));
      c32 p0 = p[i0 + 64*j], p1 = p[i1 + 64*j];
      c32 q0 = cadd(cscale(acc0[j], lq), p0);
      c32 q1 = cadd(cscale(acc1[j], lq), p1);
      q[i0 + 64*j] = q0; q[i1 + 64*j] = q1;
      pqs = cadd(pqs, cadd(cmulj(q0, p0), cmulj(q1, p1)));
    }
    pqs = wave_reduce_c(pqs);
    if (lane == 0) pqpart[b*QBLK + h] = pqs;
  }
}

// Per-iter kernel 4: self-reduce pq -> alpha; x += a p; r -= a q; |r|^2 partials.
__global__ __launch_bounds__(256)
void update1(c32* __restrict__ x, c32* __restrict__ r,
             const c32* __restrict__ p, const c32* __restrict__ q,
             const float* __restrict__ rr, const c32* __restrict__ pqpart,
             const float* __restrict__ flag, float* __restrict__ part,
             const int it)
{
  if (flag[0] == 0.f) return;
  const int b = blockIdx.y;
  const int t = threadIdx.x;
  c32 s = make_float2(0.f, 0.f);
  for (int j = t; j < QBLK; j += 256) s = cadd(s, pqpart[b*QBLK + j]);
  s = wave_reduce_c(s);
  __shared__ c32 spq[4];
  const int lane = t & 63, wv = t >> 6;
  if (lane == 0) spq[wv] = s;
  __syncthreads();
  const c32 pqv = cadd(cadd(spq[0], spq[1]), cadd(spq[2], spq[3]));
  const float rrv = rr[it*NB + b];
  const float den = pqv.x*pqv.x + pqv.y*pqv.y;
  const c32 alpha = make_float2(rrv * pqv.x / den, -rrv * pqv.y / den);
  const int hw = blockIdx.x * 256 + t;
  float acc = 0.f;
  #pragma unroll
  for (int m = 0; m < NM; ++m) {
    const size_t idx = (size_t)(b*NM + m) * NHW + hw;
    c32 pe = p[idx], qe = q[idx];
    c32 xe = cadd(x[idx], cmul(alpha, pe));
    c32 re = csub(r[idx], cmul(alpha, qe));
    x[idx] = xe; r[idx] = re;
    acc += re.x*re.x + re.y*re.y;
  }
  acc = wave_reduce_f(acc);
  __shared__ float sred[4];
  if (lane == 0) sred[wv] = acc;
  __syncthreads();
  if (t == 0) part[b*PBLK + blockIdx.x] = sred[0]+sred[1]+sred[2]+sred[3];
}

extern "C" void kernel_launch(void* const* d_in, const int* in_sizes, int n_in,
                              void* d_out, int out_size, void* d_ws, size_t ws_size,
                              hipStream_t stream)
{
  const c32*  z   = (const c32*)d_in[0];
  const c32*  y   = (const c32*)d_in[1];
  const c32*  sm  = (const c32*)d_in[2];
  const float* mk = (const float*)d_in[3];
  const float* lam= (const float*)d_in[4];
  c32* x = (c32*)d_out;

  char* base = (char*)d_ws;
  size_t off = 0;
  auto walloc = [&](size_t bytes) -> void* {
    void* ptr = base + off;
    off += (bytes + 255) & ~(size_t)255;
    return ptr;
  };
  c32* buf1   = (c32*)walloc((size_t)NBC * NHW * sizeof(c32));
  c32* buf2   = (c32*)walloc((size_t)NBC * NHW * sizeof(c32));
  c32* rv     = (c32*)walloc((size_t)NB * NM * NHW * sizeof(c32));
  c32* pvA    = (c32*)walloc((size_t)NB * NM * NHW * sizeof(c32));
  c32* pvB    = (c32*)walloc((size_t)NB * NM * NHW * sizeof(c32));
  c32* qv     = (c32*)walloc((size_t)NB * NM * NHW * sizeof(c32));
  c32* pqpart = (c32*)walloc((size_t)NB * QBLK * sizeof(c32));
  float* rr   = (float*)walloc((NITER + 1) * NB * sizeof(float));
  float* flags= (float*)walloc((NITER + 1) * sizeof(float));
  float* part1= (float*)walloc((size_t)NB * PBLK * sizeof(float));
  c32* T320   = (c32*)walloc(256 * sizeof(c32));
  c32* T64    = (c32*)walloc(32 * sizeof(c32));
  (void)ws_size; (void)in_sizes; (void)n_in; (void)out_size;

  dim3 blk256(256), blk512(512);
  dim3 fgrid(NBC, NN / 8);           // bc-major: XCD = bc % 8 (L2 producer/consumer pinning)
  dim3 qgrid(QBLK, NB);              // ifft_q: per (b, h-row)
  dim3 ugrid(PBLK, NB);              // init_combine / update1

  twiddle_init<<<1, blk256, 0, stream>>>(T320, T64);

  // ---- setup: img(buf1) = unnormalized ifft2(y * mask); x0/r/p init + |x0|^2 partials ----
  fft_pass<false, true ><<<fgrid, blk512, 0, stream>>>(y,    buf2, mk,      T320, T64);
  fft_pass<false, false><<<fgrid, blk512, 0, stream>>>(buf2, buf1, nullptr, T320, T64);
  init_combine<<<ugrid, blk256, 0, stream>>>(buf1, sm, z, x, rv, pvA, lam, part1);

  // ---- 10 CG iterations (4 kernels each) ----
  for (int i = 0; i < NITER; ++i) {
    c32* pin  = (i & 1) ? pvA : pvB;        // unused at i==0
    c32* pout = (i & 1) ? pvB : pvA;        // i=0: pvA (holds x0, not rewritten)
    fft_comb<<<fgrid, blk512, 0, stream>>>(buf2, pin, rv, pout, sm, rr, flags, part1, i, T320, T64);
    fft_mask_ifft<<<fgrid, blk512, 0, stream>>>(buf2, buf1, mk, flags + i, T320, T64);
    ifft_q<<<qgrid, blk256, 0, stream>>>(buf1, sm, pout, qv, lam, flags + i, pqpart, T320, T64);
    update1<<<ugrid, blk256, 0, stream>>>(x, rv, pout, qv, rr, pqpart, flags + i, part1, i);
  }
}